// Round 1
// baseline (5690.430 us; speedup 1.0000x reference)
//
#include <hip/hip_runtime.h>
#include <hip/hip_bf16.h>
#include <math.h>

// Problem constants
#define Dn 6
#define Bn 32
#define Cn 384
#define Hn 6
#define HDn 64
#define FFn 1536
#define NCn 10
#define IMGn 224
#define Pn 16
#define Nn 197          // tokens
#define NPATCH 196
#define SCALEf 0.125f
#define EPSf 1e-6f

// ---------------------------------------------------------------------------
// im2col: x (B,3,224,224) -> col (B*196, 768), k = i*256 + ph*16 + pw
// ---------------------------------------------------------------------------
__global__ __launch_bounds__(256) void im2col_kernel(const float* __restrict__ x,
                                                     float* __restrict__ col) {
    long idx = (long)blockIdx.x * 256 + threadIdx.x;
    const long total = (long)Bn * NPATCH * 768;
    if (idx >= total) return;
    int k = (int)(idx % 768);
    long row = idx / 768;
    int b = (int)(row / NPATCH), p = (int)(row % NPATCH);
    int i = k / 256, r = k % 256, ph = r / 16, pw = r % 16;
    int py = p / 14, px = p % 14;
    col[idx] = x[(((long)b * 3 + i) * IMGn + py * 16 + ph) * IMGn + px * 16 + pw];
}

// ---------------------------------------------------------------------------
// assemble x: x[b,0,:] = cls + pos[0]; x[b,1+p,c] = tmp[b*196+p,c] + pos[1+p,c]
// ---------------------------------------------------------------------------
__global__ __launch_bounds__(256) void assemble_kernel(const float* __restrict__ tmp,
                                                       const float* __restrict__ cls_token,
                                                       const float* __restrict__ pos,
                                                       float* __restrict__ x) {
    long idx = (long)blockIdx.x * 256 + threadIdx.x;
    const long total = (long)Bn * Nn * Cn;
    if (idx >= total) return;
    int c = (int)(idx % Cn);
    long rem = idx / Cn;
    int n = (int)(rem % Nn);
    int b = (int)(rem / Nn);
    float v;
    if (n == 0) v = cls_token[c];
    else v = tmp[((long)b * NPATCH + (n - 1)) * Cn + c];
    x[idx] = v + pos[n * Cn + c];
}

// ---------------------------------------------------------------------------
// LayerNorm over C=384, one wave per row
// ---------------------------------------------------------------------------
__global__ __launch_bounds__(64) void ln_kernel(const float* __restrict__ x,
                                                const float* __restrict__ w,
                                                const float* __restrict__ b,
                                                float* __restrict__ out) {
    long row = blockIdx.x;
    int lane = threadIdx.x;
    const float* xr = x + row * Cn;
    float v[6];
    float s = 0.f, ss = 0.f;
#pragma unroll
    for (int j = 0; j < 6; ++j) {
        v[j] = xr[lane + 64 * j];
        s += v[j];
        ss += v[j] * v[j];
    }
#pragma unroll
    for (int off = 32; off >= 1; off >>= 1) {
        s += __shfl_xor(s, off);
        ss += __shfl_xor(ss, off);
    }
    float m = s * (1.0f / Cn);
    float var = ss * (1.0f / Cn) - m * m;
    float rstd = rsqrtf(var + EPSf);
#pragma unroll
    for (int j = 0; j < 6; ++j) {
        int c = lane + 64 * j;
        out[row * Cn + c] = (v[j] - m) * rstd * w[c] + b[c];
    }
}

// ---------------------------------------------------------------------------
// Generic tiled f32 GEMM:  Out[m,o] (+)= sum_k A[m,k] * W[o,k]*(mask) + bias[o]
// EPI: 0 = store, 1 = gelu(store), 2 = residual add (Out += v)
// Per-batch via blockIdx.z: A += z*strideA, Out += z*strideO,
//   mask = maskBase + y[z]*maskClassStride (if MASK)
// ---------------------------------------------------------------------------
template <int EPI, bool MASK>
__global__ __launch_bounds__(256) void gemm_bias_kernel(
    const float* __restrict__ A, long strideA,
    const float* __restrict__ W,
    const float* __restrict__ maskBase, long maskClassStride,
    const int* __restrict__ y,
    const float* __restrict__ bias,
    float* __restrict__ Out, long strideO,
    int M, int Nout, int K) {
    int bz = blockIdx.z;
    A += (long)bz * strideA;
    Out += (long)bz * strideO;
    const float* Wm = nullptr;
    if (MASK) Wm = maskBase + (long)y[bz] * maskClassStride;

    __shared__ float As[16][65];
    __shared__ float Ws[16][65];

    int tid = threadIdx.x;
    int tx = tid & 15, ty = tid >> 4;
    int m0 = blockIdx.x * 64;
    int n0 = blockIdx.y * 64;

    float acc[4][4] = {};

    for (int k0 = 0; k0 < K; k0 += 16) {
        int r = tid >> 2;
        int kc = (tid & 3) * 4;
        {
            int m = m0 + r;
            float4 va = make_float4(0.f, 0.f, 0.f, 0.f);
            if (m < M) va = *(const float4*)(A + (long)m * K + k0 + kc);
            As[kc + 0][r] = va.x; As[kc + 1][r] = va.y;
            As[kc + 2][r] = va.z; As[kc + 3][r] = va.w;

            int o = n0 + r;
            float4 vw = make_float4(0.f, 0.f, 0.f, 0.f);
            if (o < Nout) {
                vw = *(const float4*)(W + (long)o * K + k0 + kc);
                if (MASK) {
                    const float* mr = Wm + (long)o * K + k0 + kc;
                    vw.x *= mr[0]; vw.y *= mr[1]; vw.z *= mr[2]; vw.w *= mr[3];
                }
            }
            Ws[kc + 0][r] = vw.x; Ws[kc + 1][r] = vw.y;
            Ws[kc + 2][r] = vw.z; Ws[kc + 3][r] = vw.w;
        }
        __syncthreads();
#pragma unroll
        for (int k = 0; k < 16; ++k) {
            float a[4], w4[4];
#pragma unroll
            for (int i = 0; i < 4; ++i) a[i] = As[k][ty + 16 * i];
#pragma unroll
            for (int j = 0; j < 4; ++j) w4[j] = Ws[k][tx + 16 * j];
#pragma unroll
            for (int i = 0; i < 4; ++i)
#pragma unroll
                for (int j = 0; j < 4; ++j) acc[i][j] += a[i] * w4[j];
        }
        __syncthreads();
    }

#pragma unroll
    for (int i = 0; i < 4; ++i) {
        int m = m0 + ty + 16 * i;
        if (m >= M) continue;
#pragma unroll
        for (int j = 0; j < 4; ++j) {
            int n = n0 + tx + 16 * j;
            if (n >= Nout) continue;
            float v = acc[i][j];
            if (bias) v += bias[n];
            if (EPI == 1) v = 0.5f * v * (1.0f + erff(v * 0.70710678118654752440f));
            long oi = (long)m * Nout + n;
            if (EPI == 2) Out[oi] += v;
            else Out[oi] = v;
        }
    }
}

// ---------------------------------------------------------------------------
// Fused attention scores + softmax.
// One block (256 threads) per (b, h, i): computes row i of softmax(q*SCALE@k^T)
// qkv layout: (B*N, 1152), q at +0, k at +384, v at +768 (each h*64+d)
// ---------------------------------------------------------------------------
__global__ __launch_bounds__(256) void attn_scores_softmax(const float* __restrict__ qkv,
                                                           float* __restrict__ probs) {
    int bi = blockIdx.x;             // b*H*N + h*N + i
    int i = bi % Nn;
    int bh = bi / Nn;
    int h = bh % Hn;
    int b = bh / Hn;

    __shared__ float q[64];
    __shared__ float redmax[4];
    __shared__ float redsum[4];

    const float* qr = qkv + ((long)(b * Nn + i) * (3 * Cn)) + h * HDn;
    if (threadIdx.x < 64) q[threadIdx.x] = qr[threadIdx.x];
    __syncthreads();

    int j = threadIdx.x;
    float val = -INFINITY;
    if (j < Nn) {
        const float4* kr4 = (const float4*)(qkv + ((long)(b * Nn + j) * (3 * Cn)) + Cn + h * HDn);
        const float4* q4 = (const float4*)q;
        float acc = 0.f;
#pragma unroll
        for (int d4 = 0; d4 < 16; ++d4) {
            float4 kk = kr4[d4];
            float4 qq = q4[d4];
            acc += qq.x * kk.x + qq.y * kk.y + qq.z * kk.z + qq.w * kk.w;
        }
        val = acc * SCALEf;
    }

    int lane = threadIdx.x & 63;
    int wid = threadIdx.x >> 6;

    float m = val;
#pragma unroll
    for (int off = 32; off >= 1; off >>= 1) m = fmaxf(m, __shfl_xor(m, off));
    if (lane == 0) redmax[wid] = m;
    __syncthreads();
    m = fmaxf(fmaxf(redmax[0], redmax[1]), fmaxf(redmax[2], redmax[3]));

    float e = (j < Nn) ? expf(val - m) : 0.f;
    float s = e;
#pragma unroll
    for (int off = 32; off >= 1; off >>= 1) s += __shfl_xor(s, off);
    if (lane == 0) redsum[wid] = s;
    __syncthreads();
    s = redsum[0] + redsum[1] + redsum[2] + redsum[3];

    if (j < Nn) probs[(long)bh * Nn * Nn + (long)i * Nn + j] = e / s;
}

// ---------------------------------------------------------------------------
// o[b,i,h*64+d] = (sum_j probs[b,h,i,j] * v[b,j,h,d]) * mask_attn[y[b],h,d]
// One wave per (b,h,i); lane = d.
// ---------------------------------------------------------------------------
__global__ __launch_bounds__(64) void attn_av(const float* __restrict__ probs,
                                              const float* __restrict__ qkv,
                                              const float* __restrict__ ma,  // layer ptr (NC,H,HD)
                                              const int* __restrict__ y,
                                              float* __restrict__ o) {
    int bi = blockIdx.x;
    int i = bi % Nn;
    int bh = bi / Nn;
    int h = bh % Hn;
    int b = bh / Hn;
    int lane = threadIdx.x;

    __shared__ float arow[200];
    const float* ar = probs + (long)bh * Nn * Nn + (long)i * Nn;
    for (int j = lane; j < Nn; j += 64) arow[j] = ar[j];
    __syncthreads();

    const float* vbase = qkv + (long)b * Nn * (3 * Cn) + 2 * Cn + h * HDn + lane;
    float acc = 0.f;
#pragma unroll 4
    for (int j = 0; j < Nn; ++j) acc += arow[j] * vbase[(long)j * (3 * Cn)];

    float mk = ma[(long)y[b] * (Hn * HDn) + h * HDn + lane];
    o[((long)(b * Nn + i)) * Cn + h * HDn + lane] = acc * mk;
}

// ---------------------------------------------------------------------------
// Final: LN(x[b,0,:]) with norm_w/b, then head (NC=10 outputs). One wave per b.
// ---------------------------------------------------------------------------
__global__ __launch_bounds__(64) void final_head(const float* __restrict__ x,
                                                 const float* __restrict__ nw,
                                                 const float* __restrict__ nb,
                                                 const float* __restrict__ hw,
                                                 const float* __restrict__ hb,
                                                 float* __restrict__ out) {
    int b = blockIdx.x;
    int lane = threadIdx.x;
    const float* xr = x + (long)b * Nn * Cn;  // row 0
    float v[6];
    float s = 0.f, ss = 0.f;
#pragma unroll
    for (int j = 0; j < 6; ++j) {
        v[j] = xr[lane + 64 * j];
        s += v[j];
        ss += v[j] * v[j];
    }
#pragma unroll
    for (int off = 32; off >= 1; off >>= 1) {
        s += __shfl_xor(s, off);
        ss += __shfl_xor(ss, off);
    }
    float m = s * (1.0f / Cn);
    float var = ss * (1.0f / Cn) - m * m;
    float rstd = rsqrtf(var + EPSf);
    float nvals[6];
#pragma unroll
    for (int j = 0; j < 6; ++j) {
        int c = lane + 64 * j;
        nvals[j] = (v[j] - m) * rstd * nw[c] + nb[c];
    }
    for (int c10 = 0; c10 < NCn; ++c10) {
        float p = 0.f;
#pragma unroll
        for (int j = 0; j < 6; ++j) p += nvals[j] * hw[(long)c10 * Cn + lane + 64 * j];
#pragma unroll
        for (int off = 32; off >= 1; off >>= 1) p += __shfl_xor(p, off);
        if (lane == 0) out[b * NCn + c10] = p + hb[c10];
    }
}

// ---------------------------------------------------------------------------
extern "C" void kernel_launch(void* const* d_in, const int* in_sizes, int n_in,
                              void* d_out, int out_size, void* d_ws, size_t ws_size,
                              hipStream_t stream) {
    const float* x_in     = (const float*)d_in[0];
    const int*   y        = (const int*)d_in[1];
    const float* patch_w  = (const float*)d_in[2];
    const float* patch_b  = (const float*)d_in[3];
    const float* cls_tok  = (const float*)d_in[4];
    const float* pos_emb  = (const float*)d_in[5];
    const float* n1_w     = (const float*)d_in[6];
    const float* n1_b     = (const float*)d_in[7];
    const float* qkv_w    = (const float*)d_in[8];
    const float* qkv_b    = (const float*)d_in[9];
    const float* proj_w   = (const float*)d_in[10];
    const float* proj_b   = (const float*)d_in[11];
    const float* mask_attn= (const float*)d_in[12];
    const float* mask_proj= (const float*)d_in[13];
    const float* n2_w     = (const float*)d_in[14];
    const float* n2_b     = (const float*)d_in[15];
    const float* fc1_w    = (const float*)d_in[16];
    const float* fc1_b    = (const float*)d_in[17];
    const float* fc2_w    = (const float*)d_in[18];
    const float* fc2_b    = (const float*)d_in[19];
    const float* mask_fc1 = (const float*)d_in[20];
    const float* mask_fc2 = (const float*)d_in[21];
    const float* norm_w   = (const float*)d_in[22];
    const float* norm_b   = (const float*)d_in[23];
    const float* head_w   = (const float*)d_in[24];
    const float* head_b   = (const float*)d_in[25];

    // Workspace layout (floats). Total ~126.7 MB.
    float* ws  = (float*)d_ws;
    float* X   = ws;                         // B*N*C      = 2,421,504
    float* T   = X + 2421504;                // B*N*C
    float* QKV = T + 2421504;                // B*N*3C     = 7,264,512 (also im2col: 4,816,896)
    float* SC  = QKV + 7264512;              // B*H*N*N    = 7,451,328
    float* O   = SC + 7451328;               // B*N*C
    float* FFb = O + 2421504;                // B*N*FF     = 9,682,944 (also patch tmp: 2,408,448)

    // --- patch embed ---
    {
        long tot = (long)Bn * NPATCH * 768;
        im2col_kernel<<<(int)((tot + 255) / 256), 256, 0, stream>>>(x_in, QKV);
        gemm_bias_kernel<0, false><<<dim3(98, 6, 1), 256, 0, stream>>>(
            QKV, 0, patch_w, nullptr, 0, nullptr, patch_b, FFb, 0,
            Bn * NPATCH, Cn, 768);
        long tot2 = (long)Bn * Nn * Cn;
        assemble_kernel<<<(int)((tot2 + 255) / 256), 256, 0, stream>>>(FFb, cls_tok, pos_emb, X);
    }

    const long sA = (long)Nn * Cn;      // per-batch stride of (N,C) buffers
    const long sF = (long)Nn * FFn;

    for (int l = 0; l < Dn; ++l) {
        const float* n1w  = n1_w + l * Cn;
        const float* n1b  = n1_b + l * Cn;
        const float* qw   = qkv_w + (long)l * 3 * Cn * Cn;
        const float* qb   = qkv_b + (long)l * 3 * Cn;
        const float* pw   = proj_w + (long)l * Cn * Cn;
        const float* pb   = proj_b + (long)l * Cn;
        const float* ma_l = mask_attn + (long)l * NCn * Hn * HDn;
        const float* mp_l = mask_proj + (long)l * NCn * Cn * Cn;
        const float* n2w  = n2_w + l * Cn;
        const float* n2b  = n2_b + l * Cn;
        const float* f1w  = fc1_w + (long)l * FFn * Cn;
        const float* f1b  = fc1_b + (long)l * FFn;
        const float* f2w  = fc2_w + (long)l * Cn * FFn;
        const float* f2b  = fc2_b + (long)l * Cn;
        const float* mf1_l= mask_fc1 + (long)l * NCn * FFn * Cn;
        const float* mf2_l= mask_fc2 + (long)l * NCn * Cn * FFn;

        // t = LN(x; n1)
        ln_kernel<<<Bn * Nn, 64, 0, stream>>>(X, n1w, n1b, T);
        // qkv = t @ qw^T + qb   (M=6304, N=1152, K=384)
        gemm_bias_kernel<0, false><<<dim3(99, 18, 1), 256, 0, stream>>>(
            T, 0, qw, nullptr, 0, nullptr, qb, QKV, 0, Bn * Nn, 3 * Cn, Cn);
        // probs = softmax(q*SCALE @ k^T)
        attn_scores_softmax<<<Bn * Hn * Nn, 256, 0, stream>>>(QKV, SC);
        // o = (probs @ v) * mask_attn[y]
        attn_av<<<Bn * Hn * Nn, 64, 0, stream>>>(SC, QKV, ma_l, y, O);
        // x += o @ (pw * mp[y])^T + pb
        gemm_bias_kernel<2, true><<<dim3(4, 6, Bn), 256, 0, stream>>>(
            O, sA, pw, mp_l, (long)Cn * Cn, y, pb, X, sA, Nn, Cn, Cn);
        // t = LN(x; n2)
        ln_kernel<<<Bn * Nn, 64, 0, stream>>>(X, n2w, n2b, T);
        // ff = gelu(t @ (f1w*mf1[y])^T + f1b)
        gemm_bias_kernel<1, true><<<dim3(4, 24, Bn), 256, 0, stream>>>(
            T, sA, f1w, mf1_l, (long)FFn * Cn, y, f1b, FFb, sF, Nn, FFn, Cn);
        // x += ff @ (f2w*mf2[y])^T + f2b
        gemm_bias_kernel<2, true><<<dim3(4, 6, Bn), 256, 0, stream>>>(
            FFb, sF, f2w, mf2_l, (long)Cn * FFn, y, f2b, X, sA, Nn, Cn, FFn);
    }

    // final LN (cls row only) + head
    final_head<<<Bn, 64, 0, stream>>>(X, norm_w, norm_b, head_w, head_b, (float*)d_out);
}

// Round 2
// 3725.527 us; speedup vs baseline: 1.5274x; 1.5274x over previous
//
#include <hip/hip_runtime.h>
#include <hip/hip_bf16.h>
#include <math.h>

// Problem constants
#define Dn 6
#define Bn 32
#define Cn 384
#define Hn 6
#define HDn 64
#define FFn 1536
#define NCn 10
#define IMGn 224
#define Pn 16
#define Nn 197          // tokens
#define NPATCH 196
#define SCALEf 0.125f
#define EPSf 1e-6f

typedef __attribute__((ext_vector_type(8))) short short8;
typedef __attribute__((ext_vector_type(4))) float f32x4;

__device__ __forceinline__ unsigned short f2bf(float f) {
    unsigned u = __float_as_uint(f);
    return (unsigned short)((u + 0x7FFFu + ((u >> 16) & 1u)) >> 16);
}

// ---------------------------------------------------------------------------
// im2col: x (B,3,224,224) -> col (B*196, 768), k = i*256 + ph*16 + pw
// ---------------------------------------------------------------------------
__global__ __launch_bounds__(256) void im2col_kernel(const float* __restrict__ x,
                                                     float* __restrict__ col) {
    long idx = (long)blockIdx.x * 256 + threadIdx.x;
    const long total = (long)Bn * NPATCH * 768;
    if (idx >= total) return;
    int k = (int)(idx % 768);
    long row = idx / 768;
    int b = (int)(row / NPATCH), p = (int)(row % NPATCH);
    int i = k / 256, r = k % 256, ph = r / 16, pw = r % 16;
    int py = p / 14, px = p % 14;
    col[idx] = x[(((long)b * 3 + i) * IMGn + py * 16 + ph) * IMGn + px * 16 + pw];
}

// ---------------------------------------------------------------------------
// assemble x
// ---------------------------------------------------------------------------
__global__ __launch_bounds__(256) void assemble_kernel(const float* __restrict__ tmp,
                                                       const float* __restrict__ cls_token,
                                                       const float* __restrict__ pos,
                                                       float* __restrict__ x) {
    long idx = (long)blockIdx.x * 256 + threadIdx.x;
    const long total = (long)Bn * Nn * Cn;
    if (idx >= total) return;
    int c = (int)(idx % Cn);
    long rem = idx / Cn;
    int n = (int)(rem % Nn);
    int b = (int)(rem / Nn);
    float v;
    if (n == 0) v = cls_token[c];
    else v = tmp[((long)b * NPATCH + (n - 1)) * Cn + c];
    x[idx] = v + pos[n * Cn + c];
}

// ---------------------------------------------------------------------------
// LayerNorm over C=384, one wave per row
// ---------------------------------------------------------------------------
__global__ __launch_bounds__(64) void ln_kernel(const float* __restrict__ x,
                                                const float* __restrict__ w,
                                                const float* __restrict__ b,
                                                float* __restrict__ out) {
    long row = blockIdx.x;
    int lane = threadIdx.x;
    const float* xr = x + row * Cn;
    float v[6];
    float s = 0.f, ss = 0.f;
#pragma unroll
    for (int j = 0; j < 6; ++j) {
        v[j] = xr[lane + 64 * j];
        s += v[j];
        ss += v[j] * v[j];
    }
#pragma unroll
    for (int off = 32; off >= 1; off >>= 1) {
        s += __shfl_xor(s, off);
        ss += __shfl_xor(ss, off);
    }
    float m = s * (1.0f / Cn);
    float var = ss * (1.0f / Cn) - m * m;
    float rstd = rsqrtf(var + EPSf);
#pragma unroll
    for (int j = 0; j < 6; ++j) {
        int c = lane + 64 * j;
        out[row * Cn + c] = (v[j] - m) * rstd * w[c] + b[c];
    }
}

// ---------------------------------------------------------------------------
// bf16 MFMA GEMM:  Out[m,o] (+)= sum_k A[m,k] * W[o,k]*(mask) + bias[o]
// A, W, mask are f32 in memory; converted to bf16 during LDS staging.
// Block: 256 thr (4 waves), tile M64 x N128, K-step 32.
// Wave w: wr=w>>1 (M half), wc=w&1 (N half); wave tile 32x64 = 2x4 frags.
// LDS fragment-major layout: per 16-wide subtile, lane l's 8 bf16 at l*16B.
// EPI: 0 = store, 1 = gelu, 2 = residual add. Requires N%128==0, K%32==0.
// ---------------------------------------------------------------------------
template <int EPI, bool MASK>
__global__ __launch_bounds__(256) void gemm_mfma_kernel(
    const float* __restrict__ A, long strideA,
    const float* __restrict__ W,
    const float* __restrict__ maskBase, long maskClassStride,
    const int* __restrict__ y,
    const float* __restrict__ bias,
    float* __restrict__ Out, long strideO,
    int M, int Nout, int K) {
    int bz = blockIdx.z;
    A += (long)bz * strideA;
    Out += (long)bz * strideO;
    const float* Wm = MASK ? (maskBase + (long)y[bz] * maskClassStride) : nullptr;

    __shared__ alignas(16) short Ab[64 * 32];    // 4 subtiles * 512 shorts
    __shared__ alignas(16) short Bb[128 * 32];   // 8 subtiles * 512 shorts

    const int tid = threadIdx.x;
    const int lane = tid & 63;
    const int w = tid >> 6;
    const int wr = w >> 1, wc = w & 1;
    const int m0 = blockIdx.x * 64;
    const int n0 = blockIdx.y * 128;

    const int srow = tid >> 2;   // 0..63
    const int skg = tid & 3;     // 0..3 (k-group of 8)

    f32x4 acc[2][4];
#pragma unroll
    for (int i = 0; i < 2; ++i)
#pragma unroll
        for (int j = 0; j < 4; ++j) acc[i][j] = (f32x4){0.f, 0.f, 0.f, 0.f};

    for (int k0 = 0; k0 < K; k0 += 32) {
        // ---- stage A (64 x 32)
        {
            int m = m0 + srow;
            float4 v0 = make_float4(0.f, 0.f, 0.f, 0.f);
            float4 v1 = make_float4(0.f, 0.f, 0.f, 0.f);
            if (m < M) {
                const float* src = A + (long)m * K + k0 + skg * 8;
                v0 = *(const float4*)(src);
                v1 = *(const float4*)(src + 4);
            }
            short8 p;
            p[0] = f2bf(v0.x); p[1] = f2bf(v0.y); p[2] = f2bf(v0.z); p[3] = f2bf(v0.w);
            p[4] = f2bf(v1.x); p[5] = f2bf(v1.y); p[6] = f2bf(v1.z); p[7] = f2bf(v1.w);
            *(short8*)(Ab + (srow >> 4) * 512 + (skg * 16 + (srow & 15)) * 8) = p;
        }
        // ---- stage B (32 x 128), 2 cols per thread, mask fused
#pragma unroll
        for (int cc = 0; cc < 2; ++cc) {
            int col = srow + cc * 64;
            const float* src = W + (long)(n0 + col) * K + k0 + skg * 8;
            float4 v0 = *(const float4*)(src);
            float4 v1 = *(const float4*)(src + 4);
            if (MASK) {
                const float* ms = Wm + (long)(n0 + col) * K + k0 + skg * 8;
                float4 q0 = *(const float4*)(ms);
                float4 q1 = *(const float4*)(ms + 4);
                v0.x *= q0.x; v0.y *= q0.y; v0.z *= q0.z; v0.w *= q0.w;
                v1.x *= q1.x; v1.y *= q1.y; v1.z *= q1.z; v1.w *= q1.w;
            }
            short8 p;
            p[0] = f2bf(v0.x); p[1] = f2bf(v0.y); p[2] = f2bf(v0.z); p[3] = f2bf(v0.w);
            p[4] = f2bf(v1.x); p[5] = f2bf(v1.y); p[6] = f2bf(v1.z); p[7] = f2bf(v1.w);
            *(short8*)(Bb + (col >> 4) * 512 + (skg * 16 + (col & 15)) * 8) = p;
        }
        __syncthreads();
        // ---- compute: 6 ds_read_b128 + 8 MFMA per wave
        short8 af[2], bfr[4];
#pragma unroll
        for (int i = 0; i < 2; ++i)
            af[i] = *(const short8*)(Ab + (2 * wr + i) * 512 + lane * 8);
#pragma unroll
        for (int j = 0; j < 4; ++j)
            bfr[j] = *(const short8*)(Bb + (wc * 4 + j) * 512 + lane * 8);
#pragma unroll
        for (int i = 0; i < 2; ++i)
#pragma unroll
            for (int j = 0; j < 4; ++j)
                acc[i][j] = __builtin_amdgcn_mfma_f32_16x16x32_bf16(af[i], bfr[j], acc[i][j], 0, 0, 0);
        __syncthreads();
    }

    // epilogue: D frag mapping col=lane&15, row=(lane>>4)*4+r (m89-verified)
    const int lr = lane >> 4;
    const int lc = lane & 15;
#pragma unroll
    for (int i = 0; i < 2; ++i) {
#pragma unroll
        for (int j = 0; j < 4; ++j) {
            int colg = n0 + (wc * 4 + j) * 16 + lc;
            float bv = bias ? bias[colg] : 0.f;
#pragma unroll
            for (int r = 0; r < 4; ++r) {
                int m = m0 + (2 * wr + i) * 16 + lr * 4 + r;
                if (m >= M) continue;
                float v = acc[i][j][r] + bv;
                if (EPI == 1) v = 0.5f * v * (1.0f + erff(v * 0.70710678118654752440f));
                long oi = (long)m * Nout + colg;
                if (EPI == 2) Out[oi] += v;
                else Out[oi] = v;
            }
        }
    }
}

// ---------------------------------------------------------------------------
// Fused attention scores + softmax, K staged in LDS (coalesced), pad 66.
// One block (256 threads) per (b, h, i).
// ---------------------------------------------------------------------------
__global__ __launch_bounds__(256) void attn_scores_softmax(const float* __restrict__ qkv,
                                                           float* __restrict__ probs) {
    int bi = blockIdx.x;             // b*H*N + h*N + i
    int i = bi % Nn;
    int bh = bi / Nn;
    int h = bh % Hn;
    int b = bh / Hn;

    __shared__ float Ks[Nn * 66];
    __shared__ float q[64];
    __shared__ float redmax[4];
    __shared__ float redsum[4];

    // stage K (coalesced global reads)
    const float* kbase = qkv + (long)b * Nn * (3 * Cn) + Cn + h * HDn;
    for (int idx = threadIdx.x; idx < Nn * 64; idx += 256) {
        int row = idx >> 6, d = idx & 63;
        Ks[row * 66 + d] = kbase[(long)row * (3 * Cn) + d];
    }
    const float* qr = qkv + ((long)(b * Nn + i) * (3 * Cn)) + h * HDn;
    if (threadIdx.x < 64) q[threadIdx.x] = qr[threadIdx.x];
    __syncthreads();

    int j = threadIdx.x;
    float val = -INFINITY;
    if (j < Nn) {
        const float* kr = Ks + j * 66;
        float a0 = 0.f, a1 = 0.f;
#pragma unroll
        for (int d = 0; d < 64; d += 2) {
            a0 += q[d] * kr[d];
            a1 += q[d + 1] * kr[d + 1];
        }
        val = (a0 + a1) * SCALEf;
    }

    int lane = threadIdx.x & 63;
    int wid = threadIdx.x >> 6;

    float m = val;
#pragma unroll
    for (int off = 32; off >= 1; off >>= 1) m = fmaxf(m, __shfl_xor(m, off));
    if (lane == 0) redmax[wid] = m;
    __syncthreads();
    m = fmaxf(fmaxf(redmax[0], redmax[1]), fmaxf(redmax[2], redmax[3]));

    float e = (j < Nn) ? expf(val - m) : 0.f;
    float s = e;
#pragma unroll
    for (int off = 32; off >= 1; off >>= 1) s += __shfl_xor(s, off);
    if (lane == 0) redsum[wid] = s;
    __syncthreads();
    s = redsum[0] + redsum[1] + redsum[2] + redsum[3];

    if (j < Nn) probs[(long)bh * Nn * Nn + (long)i * Nn + j] = e / s;
}

// ---------------------------------------------------------------------------
// o[b,i,h*64+d] = (sum_j probs[b,h,i,j] * v[b,j,h,d]) * mask_attn[y[b],h,d]
// ---------------------------------------------------------------------------
__global__ __launch_bounds__(64) void attn_av(const float* __restrict__ probs,
                                              const float* __restrict__ qkv,
                                              const float* __restrict__ ma,
                                              const int* __restrict__ y,
                                              float* __restrict__ o) {
    int bi = blockIdx.x;
    int i = bi % Nn;
    int bh = bi / Nn;
    int h = bh % Hn;
    int b = bh / Hn;
    int lane = threadIdx.x;

    __shared__ float arow[200];
    const float* ar = probs + (long)bh * Nn * Nn + (long)i * Nn;
    for (int j = lane; j < Nn; j += 64) arow[j] = ar[j];
    __syncthreads();

    const float* vbase = qkv + (long)b * Nn * (3 * Cn) + 2 * Cn + h * HDn + lane;
    float acc = 0.f;
#pragma unroll 4
    for (int j = 0; j < Nn; ++j) acc += arow[j] * vbase[(long)j * (3 * Cn)];

    float mk = ma[(long)y[b] * (Hn * HDn) + h * HDn + lane];
    o[((long)(b * Nn + i)) * Cn + h * HDn + lane] = acc * mk;
}

// ---------------------------------------------------------------------------
// Final: LN(x[b,0,:]) + head. One wave per b.
// ---------------------------------------------------------------------------
__global__ __launch_bounds__(64) void final_head(const float* __restrict__ x,
                                                 const float* __restrict__ nw,
                                                 const float* __restrict__ nb,
                                                 const float* __restrict__ hw,
                                                 const float* __restrict__ hb,
                                                 float* __restrict__ out) {
    int b = blockIdx.x;
    int lane = threadIdx.x;
    const float* xr = x + (long)b * Nn * Cn;  // row 0
    float v[6];
    float s = 0.f, ss = 0.f;
#pragma unroll
    for (int j = 0; j < 6; ++j) {
        v[j] = xr[lane + 64 * j];
        s += v[j];
        ss += v[j] * v[j];
    }
#pragma unroll
    for (int off = 32; off >= 1; off >>= 1) {
        s += __shfl_xor(s, off);
        ss += __shfl_xor(ss, off);
    }
    float m = s * (1.0f / Cn);
    float var = ss * (1.0f / Cn) - m * m;
    float rstd = rsqrtf(var + EPSf);
    float nvals[6];
#pragma unroll
    for (int j = 0; j < 6; ++j) {
        int c = lane + 64 * j;
        nvals[j] = (v[j] - m) * rstd * nw[c] + nb[c];
    }
    for (int c10 = 0; c10 < NCn; ++c10) {
        float p = 0.f;
#pragma unroll
        for (int j = 0; j < 6; ++j) p += nvals[j] * hw[(long)c10 * Cn + lane + 64 * j];
#pragma unroll
        for (int off = 32; off >= 1; off >>= 1) p += __shfl_xor(p, off);
        if (lane == 0) out[b * NCn + c10] = p + hb[c10];
    }
}

// ---------------------------------------------------------------------------
extern "C" void kernel_launch(void* const* d_in, const int* in_sizes, int n_in,
                              void* d_out, int out_size, void* d_ws, size_t ws_size,
                              hipStream_t stream) {
    const float* x_in     = (const float*)d_in[0];
    const int*   y        = (const int*)d_in[1];
    const float* patch_w  = (const float*)d_in[2];
    const float* patch_b  = (const float*)d_in[3];
    const float* cls_tok  = (const float*)d_in[4];
    const float* pos_emb  = (const float*)d_in[5];
    const float* n1_w     = (const float*)d_in[6];
    const float* n1_b     = (const float*)d_in[7];
    const float* qkv_w    = (const float*)d_in[8];
    const float* qkv_b    = (const float*)d_in[9];
    const float* proj_w   = (const float*)d_in[10];
    const float* proj_b   = (const float*)d_in[11];
    const float* mask_attn= (const float*)d_in[12];
    const float* mask_proj= (const float*)d_in[13];
    const float* n2_w     = (const float*)d_in[14];
    const float* n2_b     = (const float*)d_in[15];
    const float* fc1_w    = (const float*)d_in[16];
    const float* fc1_b    = (const float*)d_in[17];
    const float* fc2_w    = (const float*)d_in[18];
    const float* fc2_b    = (const float*)d_in[19];
    const float* mask_fc1 = (const float*)d_in[20];
    const float* mask_fc2 = (const float*)d_in[21];
    const float* norm_w   = (const float*)d_in[22];
    const float* norm_b   = (const float*)d_in[23];
    const float* head_w   = (const float*)d_in[24];
    const float* head_b   = (const float*)d_in[25];

    float* ws  = (float*)d_ws;
    float* X   = ws;                         // B*N*C
    float* T   = X + 2421504;                // B*N*C
    float* QKV = T + 2421504;                // B*N*3C (also im2col buffer)
    float* SC  = QKV + 7264512;              // B*H*N*N
    float* O   = SC + 7451328;               // B*N*C
    float* FFb = O + 2421504;                // B*N*FF (also patch tmp)

    // --- patch embed ---
    {
        long tot = (long)Bn * NPATCH * 768;
        im2col_kernel<<<(int)((tot + 255) / 256), 256, 0, stream>>>(x_in, QKV);
        gemm_mfma_kernel<0, false><<<dim3(98, 3, 1), 256, 0, stream>>>(
            QKV, 0, patch_w, nullptr, 0, nullptr, patch_b, FFb, 0,
            Bn * NPATCH, Cn, 768);
        long tot2 = (long)Bn * Nn * Cn;
        assemble_kernel<<<(int)((tot2 + 255) / 256), 256, 0, stream>>>(FFb, cls_tok, pos_emb, X);
    }

    const long sA = (long)Nn * Cn;
    const long sF = (long)Nn * FFn;

    for (int l = 0; l < Dn; ++l) {
        const float* n1w  = n1_w + l * Cn;
        const float* n1b  = n1_b + l * Cn;
        const float* qw   = qkv_w + (long)l * 3 * Cn * Cn;
        const float* qb   = qkv_b + (long)l * 3 * Cn;
        const float* pw   = proj_w + (long)l * Cn * Cn;
        const float* pb   = proj_b + (long)l * Cn;
        const float* ma_l = mask_attn + (long)l * NCn * Hn * HDn;
        const float* mp_l = mask_proj + (long)l * NCn * Cn * Cn;
        const float* n2w  = n2_w + l * Cn;
        const float* n2b  = n2_b + l * Cn;
        const float* f1w  = fc1_w + (long)l * FFn * Cn;
        const float* f1b  = fc1_b + (long)l * FFn;
        const float* f2w  = fc2_w + (long)l * Cn * FFn;
        const float* f2b  = fc2_b + (long)l * Cn;
        const float* mf1_l= mask_fc1 + (long)l * NCn * FFn * Cn;
        const float* mf2_l= mask_fc2 + (long)l * NCn * Cn * FFn;

        // t = LN(x; n1)
        ln_kernel<<<Bn * Nn, 64, 0, stream>>>(X, n1w, n1b, T);
        // qkv = t @ qw^T + qb   (M=6304, N=1152, K=384)
        gemm_mfma_kernel<0, false><<<dim3(99, 9, 1), 256, 0, stream>>>(
            T, 0, qw, nullptr, 0, nullptr, qb, QKV, 0, Bn * Nn, 3 * Cn, Cn);
        // probs = softmax(q*SCALE @ k^T)
        attn_scores_softmax<<<Bn * Hn * Nn, 256, 0, stream>>>(QKV, SC);
        // o = (probs @ v) * mask_attn[y]
        attn_av<<<Bn * Hn * Nn, 64, 0, stream>>>(SC, QKV, ma_l, y, O);
        // x += o @ (pw * mp[y])^T + pb
        gemm_mfma_kernel<2, true><<<dim3(4, 3, Bn), 256, 0, stream>>>(
            O, sA, pw, mp_l, (long)Cn * Cn, y, pb, X, sA, Nn, Cn, Cn);
        // t = LN(x; n2)
        ln_kernel<<<Bn * Nn, 64, 0, stream>>>(X, n2w, n2b, T);
        // ff = gelu(t @ (f1w*mf1[y])^T + f1b)
        gemm_mfma_kernel<1, true><<<dim3(4, 12, Bn), 256, 0, stream>>>(
            T, sA, f1w, mf1_l, (long)FFn * Cn, y, f1b, FFb, sF, Nn, FFn, Cn);
        // x += ff @ (f2w*mf2[y])^T + f2b
        gemm_mfma_kernel<2, true><<<dim3(4, 3, Bn), 256, 0, stream>>>(
            FFb, sF, f2w, mf2_l, (long)Cn * FFn, y, f2b, X, sA, Nn, Cn, FFn);
    }

    final_head<<<Bn, 64, 0, stream>>>(X, norm_w, norm_b, head_w, head_b, (float*)d_out);
}

// Round 3
// 1560.032 us; speedup vs baseline: 3.6476x; 2.3881x over previous
//
#include <hip/hip_runtime.h>
#include <hip/hip_bf16.h>
#include <math.h>

// Problem constants
#define Dn 6
#define Bn 32
#define Cn 384
#define Hn 6
#define HDn 64
#define FFn 1536
#define NCn 10
#define IMGn 224
#define Pn 16
#define Nn 197          // tokens
#define NPATCH 196
#define SCALEf 0.125f
#define EPSf 1e-6f

typedef __attribute__((ext_vector_type(8))) short short8;
typedef __attribute__((ext_vector_type(4))) float f32x4;

__device__ __forceinline__ unsigned short f2bf(float f) {
    unsigned u = __float_as_uint(f);
    return (unsigned short)((u + 0x7FFFu + ((u >> 16) & 1u)) >> 16);
}

__device__ __forceinline__ short8 pack8(float4 a, float4 b) {
    short8 p;
    p[0] = (short)f2bf(a.x); p[1] = (short)f2bf(a.y);
    p[2] = (short)f2bf(a.z); p[3] = (short)f2bf(a.w);
    p[4] = (short)f2bf(b.x); p[5] = (short)f2bf(b.y);
    p[6] = (short)f2bf(b.z); p[7] = (short)f2bf(b.w);
    return p;
}

// ---------------------------------------------------------------------------
// im2col: x (B,3,224,224) -> col (B*196, 768), k = i*256 + ph*16 + pw
// ---------------------------------------------------------------------------
__global__ __launch_bounds__(256) void im2col_kernel(const float* __restrict__ x,
                                                     float* __restrict__ col) {
    long idx = (long)blockIdx.x * 256 + threadIdx.x;
    const long total = (long)Bn * NPATCH * 768;
    if (idx >= total) return;
    int k = (int)(idx % 768);
    long row = idx / 768;
    int b = (int)(row / NPATCH), p = (int)(row % NPATCH);
    int i = k / 256, r = k % 256, ph = r / 16, pw = r % 16;
    int py = p / 14, px = p % 14;
    col[idx] = x[(((long)b * 3 + i) * IMGn + py * 16 + ph) * IMGn + px * 16 + pw];
}

// ---------------------------------------------------------------------------
// assemble x
// ---------------------------------------------------------------------------
__global__ __launch_bounds__(256) void assemble_kernel(const float* __restrict__ tmp,
                                                       const float* __restrict__ cls_token,
                                                       const float* __restrict__ pos,
                                                       float* __restrict__ x) {
    long idx = (long)blockIdx.x * 256 + threadIdx.x;
    const long total = (long)Bn * Nn * Cn;
    if (idx >= total) return;
    int c = (int)(idx % Cn);
    long rem = idx / Cn;
    int n = (int)(rem % Nn);
    int b = (int)(rem / Nn);
    float v;
    if (n == 0) v = cls_token[c];
    else v = tmp[((long)b * NPATCH + (n - 1)) * Cn + c];
    x[idx] = v + pos[n * Cn + c];
}

// ---------------------------------------------------------------------------
// LayerNorm over C=384, one wave per row
// ---------------------------------------------------------------------------
__global__ __launch_bounds__(64) void ln_kernel(const float* __restrict__ x,
                                                const float* __restrict__ w,
                                                const float* __restrict__ b,
                                                float* __restrict__ out) {
    long row = blockIdx.x;
    int lane = threadIdx.x;
    const float* xr = x + row * Cn;
    float v[6];
    float s = 0.f, ss = 0.f;
#pragma unroll
    for (int j = 0; j < 6; ++j) {
        v[j] = xr[lane + 64 * j];
        s += v[j];
        ss += v[j] * v[j];
    }
#pragma unroll
    for (int off = 32; off >= 1; off >>= 1) {
        s += __shfl_xor(s, off);
        ss += __shfl_xor(ss, off);
    }
    float m = s * (1.0f / Cn);
    float var = ss * (1.0f / Cn) - m * m;
    float rstd = rsqrtf(var + EPSf);
#pragma unroll
    for (int j = 0; j < 6; ++j) {
        int c = lane + 64 * j;
        out[row * Cn + c] = (v[j] - m) * rstd * w[c] + b[c];
    }
}

// ---------------------------------------------------------------------------
// bf16 MFMA GEMM, tile 128x128, K-step 32, 4 waves (2x2, each 64x64).
// Out[m,o] (+)= sum_k A[m,k]*W[o,k]*(mask) + bias[o]
// EPI: 0 = store, 1 = gelu, 2 = residual add. Requires N%128==0, K%32==0.
// ---------------------------------------------------------------------------
template <int EPI, bool MASK>
__global__ __launch_bounds__(256) void gemm_mfma_kernel(
    const float* __restrict__ A, long strideA,
    const float* __restrict__ W,
    const float* __restrict__ maskBase, long maskClassStride,
    const int* __restrict__ y,
    const float* __restrict__ bias,
    float* __restrict__ Out, long strideO,
    int M, int Nout, int K) {
    int bz = blockIdx.z;
    A += (long)bz * strideA;
    Out += (long)bz * strideO;
    const float* Wm = MASK ? (maskBase + (long)y[bz] * maskClassStride) : nullptr;

    __shared__ alignas(16) short Ab[128 * 32];   // 8 subtiles * 512
    __shared__ alignas(16) short Bb[128 * 32];

    const int tid = threadIdx.x;
    const int lane = tid & 63;
    const int w = tid >> 6;
    const int wr = w >> 1, wc = w & 1;
    const int m0 = blockIdx.x * 128;
    const int n0 = blockIdx.y * 128;

    const int srow = tid >> 2;   // 0..63
    const int skg = tid & 3;     // k-octet 0..3

    f32x4 acc[4][4];
#pragma unroll
    for (int i = 0; i < 4; ++i)
#pragma unroll
        for (int j = 0; j < 4; ++j) acc[i][j] = (f32x4){0.f, 0.f, 0.f, 0.f};

    for (int k0 = 0; k0 < K; k0 += 32) {
        // ---- stage A (128 x 32)
#pragma unroll
        for (int half = 0; half < 2; ++half) {
            int r = srow + half * 64;
            int m = m0 + r;
            float4 v0 = make_float4(0.f, 0.f, 0.f, 0.f);
            float4 v1 = make_float4(0.f, 0.f, 0.f, 0.f);
            if (m < M) {
                const float* src = A + (long)m * K + k0 + skg * 8;
                v0 = *(const float4*)(src);
                v1 = *(const float4*)(src + 4);
            }
            *(short8*)(Ab + (r >> 4) * 512 + (skg * 16 + (r & 15)) * 8) = pack8(v0, v1);
        }
        // ---- stage B (32 x 128), mask fused
#pragma unroll
        for (int half = 0; half < 2; ++half) {
            int col = srow + half * 64;
            const float* src = W + (long)(n0 + col) * K + k0 + skg * 8;
            float4 v0 = *(const float4*)(src);
            float4 v1 = *(const float4*)(src + 4);
            if (MASK) {
                const float* ms = Wm + (long)(n0 + col) * K + k0 + skg * 8;
                float4 q0 = *(const float4*)(ms);
                float4 q1 = *(const float4*)(ms + 4);
                v0.x *= q0.x; v0.y *= q0.y; v0.z *= q0.z; v0.w *= q0.w;
                v1.x *= q1.x; v1.y *= q1.y; v1.z *= q1.z; v1.w *= q1.w;
            }
            *(short8*)(Bb + (col >> 4) * 512 + (skg * 16 + (col & 15)) * 8) = pack8(v0, v1);
        }
        __syncthreads();
        // ---- compute: 8 ds_read_b128 + 16 MFMA per wave
        short8 af[4], bfr[4];
#pragma unroll
        for (int i = 0; i < 4; ++i)
            af[i] = *(const short8*)(Ab + (wr * 4 + i) * 512 + lane * 8);
#pragma unroll
        for (int j = 0; j < 4; ++j)
            bfr[j] = *(const short8*)(Bb + (wc * 4 + j) * 512 + lane * 8);
#pragma unroll
        for (int i = 0; i < 4; ++i)
#pragma unroll
            for (int j = 0; j < 4; ++j)
                acc[i][j] = __builtin_amdgcn_mfma_f32_16x16x32_bf16(af[i], bfr[j], acc[i][j], 0, 0, 0);
        __syncthreads();
    }

    // epilogue: D frag mapping col=lane&15, row=(lane>>4)*4+r
    const int lr = lane >> 4;
    const int lc = lane & 15;
#pragma unroll
    for (int i = 0; i < 4; ++i) {
#pragma unroll
        for (int j = 0; j < 4; ++j) {
            int colg = n0 + (wc * 4 + j) * 16 + lc;
            float bv = bias ? bias[colg] : 0.f;
#pragma unroll
            for (int r = 0; r < 4; ++r) {
                int m = m0 + (wr * 4 + i) * 16 + lr * 4 + r;
                if (m >= M) continue;
                float v = acc[i][j][r] + bv;
                if (EPI == 1) v = 0.5f * v * (1.0f + erff(v * 0.70710678118654752440f));
                long oi = (long)m * Nout + colg;
                if (EPI == 2) Out[oi] += v;
                else Out[oi] = v;
            }
        }
    }
}

// ---------------------------------------------------------------------------
// Fused attention: one block per (i-tile of 64 rows, b*H+h).
// S = (Q*SCALE)@K^T via MFMA, in-register softmax, P@V via MFMA,
// epilogue fuses mask_attn[y[b]]. All operands bf16, f32 accumulate.
// ---------------------------------------------------------------------------
__global__ __launch_bounds__(256) void attn_fused(const float* __restrict__ qkv,
                                                  const float* __restrict__ ma,
                                                  const int* __restrict__ y,
                                                  float* __restrict__ O) {
    const int it = blockIdx.x;       // 0..3
    const int bh = blockIdx.y;       // b*H + h
    const int h = bh % Hn, b = bh / Hn;
    const int i0 = it * 64;
    const int tid = threadIdx.x, lane = tid & 63, w = tid >> 6;
    const int lg = lane >> 4, lc = lane & 15;

    // LDS: Qb 4096 | Kb 13312 ; Vb (14336) reuses [0..); Pb at 17408 (14336)
    __shared__ alignas(16) short SH[31744];
    short* Qb = SH;
    short* Kb = SH + 4096;
    short* Vb = SH;
    short* Pb = SH + 17408;

    const float* qkv_b = qkv + (long)b * Nn * (3 * Cn);
    const int srow = tid >> 2, skg = tid & 3;

    // ---- stage Q (64 x 64), scaled by SCALE
#pragma unroll
    for (int gi = 0; gi < 2; ++gi) {
        int g = skg + gi * 4;        // d-octet 0..7
        int row = i0 + srow;
        float4 v0 = make_float4(0.f, 0.f, 0.f, 0.f);
        float4 v1 = make_float4(0.f, 0.f, 0.f, 0.f);
        if (row < Nn) {
            const float* src = qkv_b + (long)row * (3 * Cn) + h * HDn + g * 8;
            v0 = *(const float4*)(src);
            v1 = *(const float4*)(src + 4);
        }
        v0.x *= SCALEf; v0.y *= SCALEf; v0.z *= SCALEf; v0.w *= SCALEf;
        v1.x *= SCALEf; v1.y *= SCALEf; v1.z *= SCALEf; v1.w *= SCALEf;
        *(short8*)(Qb + ((srow >> 4) * 2 + (g >> 2)) * 512 +
                   ((g & 3) * 16 + (srow & 15)) * 8) = pack8(v0, v1);
    }
    // ---- stage K (208 x 64), zero-padded cols >=197
#pragma unroll
    for (int cb = 0; cb < 4; ++cb) {
        int col = srow + cb * 64;
        if (col < 208) {
#pragma unroll
            for (int gi = 0; gi < 2; ++gi) {
                int g = skg + gi * 4;
                float4 v0 = make_float4(0.f, 0.f, 0.f, 0.f);
                float4 v1 = make_float4(0.f, 0.f, 0.f, 0.f);
                if (col < Nn) {
                    const float* src = qkv_b + (long)col * (3 * Cn) + Cn + h * HDn + g * 8;
                    v0 = *(const float4*)(src);
                    v1 = *(const float4*)(src + 4);
                }
                *(short8*)(Kb + ((col >> 4) * 2 + (g >> 2)) * 512 +
                           ((g & 3) * 16 + (col & 15)) * 8) = pack8(v0, v1);
            }
        }
    }
    __syncthreads();

    // ---- S = Q @ K^T : wave w computes rows [i0+w*16, +16) x 208 cols
    f32x4 s[13];
#pragma unroll
    for (int jf = 0; jf < 13; ++jf) s[jf] = (f32x4){0.f, 0.f, 0.f, 0.f};
    {
        short8 a0 = *(const short8*)(Qb + (w * 2 + 0) * 512 + lane * 8);
        short8 a1 = *(const short8*)(Qb + (w * 2 + 1) * 512 + lane * 8);
#pragma unroll
        for (int jf = 0; jf < 13; ++jf) {
            short8 b0 = *(const short8*)(Kb + (jf * 2 + 0) * 512 + lane * 8);
            short8 b1 = *(const short8*)(Kb + (jf * 2 + 1) * 512 + lane * 8);
            s[jf] = __builtin_amdgcn_mfma_f32_16x16x32_bf16(a0, b0, s[jf], 0, 0, 0);
            s[jf] = __builtin_amdgcn_mfma_f32_16x16x32_bf16(a1, b1, s[jf], 0, 0, 0);
        }
    }

    // ---- in-register softmax over cols (rows spread across lc=0..15)
#pragma unroll
    for (int r = 0; r < 4; ++r) {
        float mx = -1e30f;
#pragma unroll
        for (int jf = 0; jf < 13; ++jf) {
            float v = s[jf][r];
            if (jf * 16 + lc > 196) v = -1e30f;
            mx = fmaxf(mx, v);
        }
#pragma unroll
        for (int off = 1; off <= 8; off <<= 1) mx = fmaxf(mx, __shfl_xor(mx, off));
        float sum = 0.f;
#pragma unroll
        for (int jf = 0; jf < 13; ++jf) {
            float e = (jf * 16 + lc <= 196) ? __expf(s[jf][r] - mx) : 0.f;
            s[jf][r] = e;
            sum += e;
        }
#pragma unroll
        for (int off = 1; off <= 8; off <<= 1) sum += __shfl_xor(sum, off);
        float inv = 1.0f / sum;
#pragma unroll
        for (int jf = 0; jf < 13; ++jf) s[jf][r] *= inv;
    }
    __syncthreads();  // done reading Qb/Kb

    // ---- scatter P -> Pb (A-operand layout, k=col), zero-fill k 208..223
    if (lane < 32) {
        short8 z = {0, 0, 0, 0, 0, 0, 0, 0};
        *(short8*)(Pb + (w * 7 + 6) * 512 + (32 + lane) * 8) = z;
    }
#pragma unroll
    for (int jf = 0; jf < 13; ++jf) {
#pragma unroll
        for (int r = 0; r < 4; ++r) {
            int col = jf * 16 + lc;
            int row = lg * 4 + r;
            Pb[(w * 7 + (col >> 5)) * 512 + (((col >> 3) & 3) * 16 + row) * 8 + (col & 7)] =
                (short)f2bf(s[jf][r]);
        }
    }
    // ---- stage V (224 x 64): coalesced reads, b128 writes; zero j>=197
    {
        const float* vbase = qkv_b + 2 * Cn + h * HDn;
        int d = tid & 63;
#pragma unroll
        for (int k = 0; k < 7; ++k) {
            int jo = (tid >> 6) + 4 * k;     // 0..27
            short8 p;
#pragma unroll
            for (int t = 0; t < 8; ++t) {
                int j = jo * 8 + t;
                float v = (j < Nn) ? vbase[(long)j * (3 * Cn) + d] : 0.f;
                p[t] = (short)f2bf(v);
            }
            *(short8*)(Vb + (d >> 4) * (7 * 512) + (jo >> 2) * 512 +
                       ((jo & 3) * 16 + (d & 15)) * 8) = p;
        }
    }
    __syncthreads();

    // ---- O = P @ V : wave w rows, 4 d-subtiles
    f32x4 o[4];
#pragma unroll
    for (int df = 0; df < 4; ++df) o[df] = (f32x4){0.f, 0.f, 0.f, 0.f};
#pragma unroll
    for (int ks = 0; ks < 7; ++ks) {
        short8 pa = *(const short8*)(Pb + (w * 7 + ks) * 512 + lane * 8);
#pragma unroll
        for (int df = 0; df < 4; ++df) {
            short8 vb = *(const short8*)(Vb + (df * 7 + ks) * 512 + lane * 8);
            o[df] = __builtin_amdgcn_mfma_f32_16x16x32_bf16(pa, vb, o[df], 0, 0, 0);
        }
    }

    // ---- epilogue: * mask_attn[y[b],h,d], store f32
    const float* mar = ma + (long)y[b] * (Hn * HDn) + h * HDn;
#pragma unroll
    for (int df = 0; df < 4; ++df) {
        int dcol = df * 16 + lc;
        float mk = mar[dcol];
#pragma unroll
        for (int r = 0; r < 4; ++r) {
            int i = i0 + w * 16 + lg * 4 + r;
            if (i < Nn) O[((long)(b * Nn + i)) * Cn + h * HDn + dcol] = o[df][r] * mk;
        }
    }
}

// ---------------------------------------------------------------------------
// Final: LN(x[b,0,:]) + head. One wave per b.
// ---------------------------------------------------------------------------
__global__ __launch_bounds__(64) void final_head(const float* __restrict__ x,
                                                 const float* __restrict__ nw,
                                                 const float* __restrict__ nb,
                                                 const float* __restrict__ hw,
                                                 const float* __restrict__ hb,
                                                 float* __restrict__ out) {
    int b = blockIdx.x;
    int lane = threadIdx.x;
    const float* xr = x + (long)b * Nn * Cn;  // row 0
    float v[6];
    float s = 0.f, ss = 0.f;
#pragma unroll
    for (int j = 0; j < 6; ++j) {
        v[j] = xr[lane + 64 * j];
        s += v[j];
        ss += v[j] * v[j];
    }
#pragma unroll
    for (int off = 32; off >= 1; off >>= 1) {
        s += __shfl_xor(s, off);
        ss += __shfl_xor(ss, off);
    }
    float m = s * (1.0f / Cn);
    float var = ss * (1.0f / Cn) - m * m;
    float rstd = rsqrtf(var + EPSf);
    float nvals[6];
#pragma unroll
    for (int j = 0; j < 6; ++j) {
        int c = lane + 64 * j;
        nvals[j] = (v[j] - m) * rstd * nw[c] + nb[c];
    }
    for (int c10 = 0; c10 < NCn; ++c10) {
        float p = 0.f;
#pragma unroll
        for (int j = 0; j < 6; ++j) p += nvals[j] * hw[(long)c10 * Cn + lane + 64 * j];
#pragma unroll
        for (int off = 32; off >= 1; off >>= 1) p += __shfl_xor(p, off);
        if (lane == 0) out[b * NCn + c10] = p + hb[c10];
    }
}

// ---------------------------------------------------------------------------
extern "C" void kernel_launch(void* const* d_in, const int* in_sizes, int n_in,
                              void* d_out, int out_size, void* d_ws, size_t ws_size,
                              hipStream_t stream) {
    const float* x_in     = (const float*)d_in[0];
    const int*   y        = (const int*)d_in[1];
    const float* patch_w  = (const float*)d_in[2];
    const float* patch_b  = (const float*)d_in[3];
    const float* cls_tok  = (const float*)d_in[4];
    const float* pos_emb  = (const float*)d_in[5];
    const float* n1_w     = (const float*)d_in[6];
    const float* n1_b     = (const float*)d_in[7];
    const float* qkv_w    = (const float*)d_in[8];
    const float* qkv_b    = (const float*)d_in[9];
    const float* proj_w   = (const float*)d_in[10];
    const float* proj_b   = (const float*)d_in[11];
    const float* mask_attn= (const float*)d_in[12];
    const float* mask_proj= (const float*)d_in[13];
    const float* n2_w     = (const float*)d_in[14];
    const float* n2_b     = (const float*)d_in[15];
    const float* fc1_w    = (const float*)d_in[16];
    const float* fc1_b    = (const float*)d_in[17];
    const float* fc2_w    = (const float*)d_in[18];
    const float* fc2_b    = (const float*)d_in[19];
    const float* mask_fc1 = (const float*)d_in[20];
    const float* mask_fc2 = (const float*)d_in[21];
    const float* norm_w   = (const float*)d_in[22];
    const float* norm_b   = (const float*)d_in[23];
    const float* head_w   = (const float*)d_in[24];
    const float* head_b   = (const float*)d_in[25];

    float* ws  = (float*)d_ws;
    float* X   = ws;                         // B*N*C
    float* T   = X + 2421504;                // B*N*C
    float* QKV = T + 2421504;                // B*N*3C (also im2col buffer)
    float* O   = QKV + 7264512;              // B*N*C
    float* FFb = O + 2421504;                // B*N*FF (also patch tmp)

    // --- patch embed ---
    {
        long tot = (long)Bn * NPATCH * 768;
        im2col_kernel<<<(int)((tot + 255) / 256), 256, 0, stream>>>(x_in, QKV);
        gemm_mfma_kernel<0, false><<<dim3(49, 3, 1), 256, 0, stream>>>(
            QKV, 0, patch_w, nullptr, 0, nullptr, patch_b, FFb, 0,
            Bn * NPATCH, Cn, 768);
        long tot2 = (long)Bn * Nn * Cn;
        assemble_kernel<<<(int)((tot2 + 255) / 256), 256, 0, stream>>>(FFb, cls_tok, pos_emb, X);
    }

    const long sA = (long)Nn * Cn;
    const long sF = (long)Nn * FFn;

    for (int l = 0; l < Dn; ++l) {
        const float* n1w  = n1_w + l * Cn;
        const float* n1b  = n1_b + l * Cn;
        const float* qw   = qkv_w + (long)l * 3 * Cn * Cn;
        const float* qb   = qkv_b + (long)l * 3 * Cn;
        const float* pw   = proj_w + (long)l * Cn * Cn;
        const float* pb   = proj_b + (long)l * Cn;
        const float* ma_l = mask_attn + (long)l * NCn * Hn * HDn;
        const float* mp_l = mask_proj + (long)l * NCn * Cn * Cn;
        const float* n2w  = n2_w + l * Cn;
        const float* n2b  = n2_b + l * Cn;
        const float* f1w  = fc1_w + (long)l * FFn * Cn;
        const float* f1b  = fc1_b + (long)l * FFn;
        const float* f2w  = fc2_w + (long)l * Cn * FFn;
        const float* f2b  = fc2_b + (long)l * Cn;
        const float* mf1_l= mask_fc1 + (long)l * NCn * FFn * Cn;
        const float* mf2_l= mask_fc2 + (long)l * NCn * Cn * FFn;

        // t = LN(x; n1)
        ln_kernel<<<Bn * Nn, 64, 0, stream>>>(X, n1w, n1b, T);
        // qkv = t @ qw^T + qb   (M=6304, N=1152, K=384)
        gemm_mfma_kernel<0, false><<<dim3(50, 9, 1), 256, 0, stream>>>(
            T, 0, qw, nullptr, 0, nullptr, qb, QKV, 0, Bn * Nn, 3 * Cn, Cn);
        // fused attention: S -> softmax -> PV -> *mask_attn[y]
        attn_fused<<<dim3(4, Bn * Hn), 256, 0, stream>>>(QKV, ma_l, y, O);
        // x += o @ (pw * mp[y])^T + pb
        gemm_mfma_kernel<2, true><<<dim3(2, 3, Bn), 256, 0, stream>>>(
            O, sA, pw, mp_l, (long)Cn * Cn, y, pb, X, sA, Nn, Cn, Cn);
        // t = LN(x; n2)
        ln_kernel<<<Bn * Nn, 64, 0, stream>>>(X, n2w, n2b, T);
        // ff = gelu(t @ (f1w*mf1[y])^T + f1b)
        gemm_mfma_kernel<1, true><<<dim3(2, 12, Bn), 256, 0, stream>>>(
            T, sA, f1w, mf1_l, (long)FFn * Cn, y, f1b, FFb, sF, Nn, FFn, Cn);
        // x += ff @ (f2w*mf2[y])^T + f2b
        gemm_mfma_kernel<2, true><<<dim3(2, 3, Bn), 256, 0, stream>>>(
            FFb, sF, f2w, mf2_l, (long)Cn * FFn, y, f2b, X, sA, Nn, Cn, FFn);
    }

    final_head<<<Bn, 64, 0, stream>>>(X, norm_w, norm_b, head_w, head_b, (float*)d_out);
}

// Round 4
// 1089.139 us; speedup vs baseline: 5.2247x; 1.4324x over previous
//
#include <hip/hip_runtime.h>
#include <hip/hip_bf16.h>
#include <math.h>

// Problem constants
#define Dn 6
#define Bn 32
#define Cn 384
#define Hn 6
#define HDn 64
#define FFn 1536
#define NCn 10
#define IMGn 224
#define Nn 197
#define NPATCH 196
#define RP 256            // padded rows per batch
#define SCALEf 0.125f
#define EPSf 1e-6f

typedef unsigned short u16;
typedef __attribute__((ext_vector_type(8))) short short8;
typedef __attribute__((ext_vector_type(4))) float f32x4;

__device__ __forceinline__ u16 f2bf(float f) {
    unsigned u = __float_as_uint(f);
    return (u16)((u + 0x7FFFu + ((u >> 16) & 1u)) >> 16);
}

__device__ __forceinline__ void gload16(const void* g, void* l) {
    __builtin_amdgcn_global_load_lds((const __attribute__((address_space(1))) void*)g,
                                     (__attribute__((address_space(3))) void*)l, 16, 0, 0);
}

// ---------------------------------------------------------------------------
// cvt f32 -> bf16, 8 elems/thread, count % 2048 == 0
// ---------------------------------------------------------------------------
__global__ __launch_bounds__(256) void cvtbf_kernel(const float* __restrict__ in,
                                                    u16* __restrict__ out) {
    long off = ((long)blockIdx.x * 256 + threadIdx.x) * 8;
    float4 v0 = *(const float4*)(in + off);
    float4 v1 = *(const float4*)(in + off + 4);
    short8 p;
    p[0] = f2bf(v0.x); p[1] = f2bf(v0.y); p[2] = f2bf(v0.z); p[3] = f2bf(v0.w);
    p[4] = f2bf(v1.x); p[5] = f2bf(v1.y); p[6] = f2bf(v1.z); p[7] = f2bf(v1.w);
    *(short8*)(out + off) = p;
}

// ---------------------------------------------------------------------------
// masked weight precompute: out[c*NK + i] = bf16(W[i] * mask[c*NK + i])
// grid (NK/2048, NC)
// ---------------------------------------------------------------------------
__global__ __launch_bounds__(256) void maskmul_kernel(const float* __restrict__ W,
                                                      const float* __restrict__ mask,
                                                      u16* __restrict__ out, int NK) {
    int c = blockIdx.y;
    long off = ((long)blockIdx.x * 256 + threadIdx.x) * 8;
    long coff = (long)c * NK + off;
    float4 w0 = *(const float4*)(W + off);
    float4 w1 = *(const float4*)(W + off + 4);
    float4 m0 = *(const float4*)(mask + coff);
    float4 m1 = *(const float4*)(mask + coff + 4);
    short8 p;
    p[0] = f2bf(w0.x * m0.x); p[1] = f2bf(w0.y * m0.y);
    p[2] = f2bf(w0.z * m0.z); p[3] = f2bf(w0.w * m0.w);
    p[4] = f2bf(w1.x * m1.x); p[5] = f2bf(w1.y * m1.y);
    p[6] = f2bf(w1.z * m1.z); p[7] = f2bf(w1.w * m1.w);
    *(short8*)(out + coff) = p;
}

// ---------------------------------------------------------------------------
// im2col -> bf16: x (B,3,224,224) -> col (B*196, 768)
// ---------------------------------------------------------------------------
__global__ __launch_bounds__(256) void im2col_kernel(const float* __restrict__ x,
                                                     u16* __restrict__ col) {
    long idx = (long)blockIdx.x * 256 + threadIdx.x;
    int k = (int)(idx % 768);
    long row = idx / 768;
    int b = (int)(row / NPATCH), p = (int)(row % NPATCH);
    int i = k / 256, r = k % 256, ph = r / 16, pw = r % 16;
    int py = p / 14, px = p % 14;
    col[idx] = f2bf(x[(((long)b * 3 + i) * IMGn + py * 16 + ph) * IMGn + px * 16 + pw]);
}

// ---------------------------------------------------------------------------
// assemble x (f32, padded): x[b*RP+0] = cls+pos[0]; x[b*RP+1+p] = tmp + pos
// ---------------------------------------------------------------------------
__global__ __launch_bounds__(256) void assemble_kernel(const float* __restrict__ tmp,
                                                       const float* __restrict__ cls_token,
                                                       const float* __restrict__ pos,
                                                       float* __restrict__ x) {
    long idx = (long)blockIdx.x * 256 + threadIdx.x;
    const long total = (long)Bn * Nn * Cn;
    if (idx >= total) return;
    int c = (int)(idx % Cn);
    long rem = idx / Cn;
    int n = (int)(rem % Nn);
    int b = (int)(rem / Nn);
    float v;
    if (n == 0) v = cls_token[c];
    else v = tmp[((long)b * NPATCH + (n - 1)) * Cn + c];
    x[((long)b * RP + n) * Cn + c] = v + pos[n * Cn + c];
}

// ---------------------------------------------------------------------------
// LayerNorm: X f32 padded -> T bf16 padded. One wave per (b,n) row.
// ---------------------------------------------------------------------------
__global__ __launch_bounds__(64) void ln_kernel(const float* __restrict__ x,
                                                const float* __restrict__ w,
                                                const float* __restrict__ b,
                                                u16* __restrict__ out) {
    long blk = blockIdx.x;
    int bb = (int)(blk / Nn), n = (int)(blk % Nn);
    long row = (long)bb * RP + n;
    int lane = threadIdx.x;
    const float* xr = x + row * Cn;
    float v[6];
    float s = 0.f, ss = 0.f;
#pragma unroll
    for (int j = 0; j < 6; ++j) {
        v[j] = xr[lane + 64 * j];
        s += v[j];
        ss += v[j] * v[j];
    }
#pragma unroll
    for (int off = 32; off >= 1; off >>= 1) {
        s += __shfl_xor(s, off);
        ss += __shfl_xor(ss, off);
    }
    float m = s * (1.0f / Cn);
    float var = ss * (1.0f / Cn) - m * m;
    float rstd = rsqrtf(var + EPSf);
#pragma unroll
    for (int j = 0; j < 6; ++j) {
        int c = lane + 64 * j;
        out[row * Cn + c] = f2bf((v[j] - m) * rstd * w[c] + b[c]);
    }
}

// ---------------------------------------------------------------------------
// bf16 MFMA GEMM, tile 128x128, K-step 32, global_load_lds staging.
// Out[m,o] (+)= sum_k A[m,k]*W[o,k] + bias[o]
// EPI: 0 = store bf16, 1 = gelu+store bf16, 2 = f32 += (atomic if KSPLIT>1),
//      3 = store f32.  All dims: M%128==0 (padded), N%128==0, K%(32*KSPLIT)==0.
// grid: (M/128, NTILES*KSPLIT, Z)
// ---------------------------------------------------------------------------
template <int EPI, int KSPLIT>
__global__ __launch_bounds__(256) void gemm_bf16(
    const u16* __restrict__ A, long strideA,
    const u16* __restrict__ Wb, long wClassStride,
    const int* __restrict__ y,
    const float* __restrict__ bias,
    void* __restrict__ OutV, long strideO,
    int Nout, int Ktot, int NTILES) {
    const int bz = blockIdx.z;
    const int nt = blockIdx.y % NTILES;
    const int ks = blockIdx.y / NTILES;
    const int K2 = Ktot / KSPLIT;
    const int kbeg = ks * K2;
    A += (long)bz * strideA;
    const u16* Wp = Wb + (y ? (long)y[bz] * wClassStride : 0);

    __shared__ alignas(16) u16 Ab[4096];   // 8 subtiles x 512
    __shared__ alignas(16) u16 Bb[4096];

    const int tid = threadIdx.x;
    const int lane = tid & 63;
    const int w = tid >> 6;
    const int wr = w >> 1, wc = w & 1;
    const int m0 = blockIdx.x * 128;
    const int n0 = nt * 128;

    // staging coords: wave w stages subtiles 2w, 2w+1 of A and B
    const int srow = 2 * w * 16 + (lane & 15);   // row/col within tile for subtile 2w
    const int gk = (lane >> 4) * 8;              // k-octet offset

    f32x4 acc[4][4];
#pragma unroll
    for (int i = 0; i < 4; ++i)
#pragma unroll
        for (int j = 0; j < 4; ++j) acc[i][j] = (f32x4){0.f, 0.f, 0.f, 0.f};

    for (int k0 = kbeg; k0 < kbeg + K2; k0 += 32) {
        const u16* a0 = A + (long)(m0 + srow) * Ktot + k0 + gk;
        const u16* b0 = Wp + (long)(n0 + srow) * Ktot + k0 + gk;
        gload16(a0, Ab + 2 * w * 512);
        gload16(a0 + 16 * (long)Ktot, Ab + (2 * w + 1) * 512);
        gload16(b0, Bb + 2 * w * 512);
        gload16(b0 + 16 * (long)Ktot, Bb + (2 * w + 1) * 512);
        __syncthreads();
        short8 af[4], bfr[4];
#pragma unroll
        for (int i = 0; i < 4; ++i)
            af[i] = *(const short8*)(Ab + (wr * 4 + i) * 512 + lane * 8);
#pragma unroll
        for (int j = 0; j < 4; ++j)
            bfr[j] = *(const short8*)(Bb + (wc * 4 + j) * 512 + lane * 8);
#pragma unroll
        for (int i = 0; i < 4; ++i)
#pragma unroll
            for (int j = 0; j < 4; ++j)
                acc[i][j] = __builtin_amdgcn_mfma_f32_16x16x32_bf16(af[i], bfr[j], acc[i][j], 0, 0, 0);
        __syncthreads();
    }

    // epilogue: D frag mapping col=lane&15, row=(lane>>4)*4+r
    const int lr = lane >> 4;
    const int lc = lane & 15;
#pragma unroll
    for (int i = 0; i < 4; ++i) {
#pragma unroll
        for (int j = 0; j < 4; ++j) {
            int colg = n0 + (wc * 4 + j) * 16 + lc;
            float bv = (bias && ks == 0) ? bias[colg] : 0.f;
#pragma unroll
            for (int r = 0; r < 4; ++r) {
                int m = m0 + (wr * 4 + i) * 16 + lr * 4 + r;
                float v = acc[i][j][r] + bv;
                long oi = (long)m * Nout + colg;
                if (EPI == 0) {
                    ((u16*)OutV + (long)bz * strideO)[oi] = f2bf(v);
                } else if (EPI == 1) {
                    v = 0.5f * v * (1.0f + erff(v * 0.70710678118654752440f));
                    ((u16*)OutV + (long)bz * strideO)[oi] = f2bf(v);
                } else if (EPI == 2) {
                    float* Out = (float*)OutV + (long)bz * strideO;
                    if (KSPLIT > 1) atomicAdd(Out + oi, v);
                    else Out[oi] += v;
                } else {
                    ((float*)OutV + (long)bz * strideO)[oi] = v;
                }
            }
        }
    }
}

// ---------------------------------------------------------------------------
// Fused attention on bf16 QKV (padded RP rows/batch).
// One block per (i-tile of 64 rows, b*H+h). S=(Q@K^T)*SCALE -> softmax -> P@V,
// epilogue fuses mask_attn[y[b]], stores bf16 O (padded).
// ---------------------------------------------------------------------------
__global__ __launch_bounds__(256) void attn_fused(const u16* __restrict__ qkv,
                                                  const float* __restrict__ ma,
                                                  const int* __restrict__ y,
                                                  u16* __restrict__ O) {
    const int it = blockIdx.x;       // 0..3
    const int bh = blockIdx.y;       // b*H + h
    const int h = bh % Hn, b = bh / Hn;
    const int i0 = it * 64;
    const int tid = threadIdx.x, lane = tid & 63, w = tid >> 6;
    const int lg = lane >> 4, lc = lane & 15;

    // LDS: Qb 4096 | Kb 13312 ; Vb (14336) reuses [0..); Pb at 17408 (14336)
    __shared__ alignas(16) u16 SH[31744];
    u16* Qb = SH;
    u16* Kb = SH + 4096;
    u16* Vb = SH;
    u16* Pb = SH + 17408;

    const u16* qkv_b = qkv + (long)b * RP * (3 * Cn);
    const int r15 = lane & 15;
    const int oct = lane >> 4;       // octet within group

    // ---- stage Q (64 x 64): 8 subtiles, 2 per wave
#pragma unroll
    for (int si = 0; si < 2; ++si) {
        int s = w * 2 + si;                        // 0..7
        int r = (s >> 1) * 16 + r15;
        int g = (s & 1) * 4 + oct;
        const u16* src = qkv_b + (long)(i0 + r) * (3 * Cn) + h * HDn + g * 8;
        gload16(src, Qb + s * 512);
    }
    // ---- stage K (208 x 64): 26 subtiles
    for (int s = w; s < 26; s += 4) {
        int c = (s >> 1) * 16 + r15;               // col 0..207 (<=255 pad ok)
        int g = (s & 1) * 4 + oct;
        const u16* src = qkv_b + (long)c * (3 * Cn) + Cn + h * HDn + g * 8;
        gload16(src, Kb + s * 512);
    }
    __syncthreads();

    // ---- S = Q @ K^T : wave w computes rows [i0+w*16, +16) x 208 cols
    f32x4 s[13];
#pragma unroll
    for (int jf = 0; jf < 13; ++jf) s[jf] = (f32x4){0.f, 0.f, 0.f, 0.f};
    {
        short8 a0 = *(const short8*)(Qb + (w * 2 + 0) * 512 + lane * 8);
        short8 a1 = *(const short8*)(Qb + (w * 2 + 1) * 512 + lane * 8);
#pragma unroll
        for (int jf = 0; jf < 13; ++jf) {
            short8 b0 = *(const short8*)(Kb + (jf * 2 + 0) * 512 + lane * 8);
            short8 b1 = *(const short8*)(Kb + (jf * 2 + 1) * 512 + lane * 8);
            s[jf] = __builtin_amdgcn_mfma_f32_16x16x32_bf16(a0, b0, s[jf], 0, 0, 0);
            s[jf] = __builtin_amdgcn_mfma_f32_16x16x32_bf16(a1, b1, s[jf], 0, 0, 0);
        }
    }

    // ---- in-register softmax (scale fused here)
#pragma unroll
    for (int r = 0; r < 4; ++r) {
        float mx = -1e30f;
#pragma unroll
        for (int jf = 0; jf < 13; ++jf) {
            float v = s[jf][r] * SCALEf;
            if (jf * 16 + lc > 196) v = -1e30f;
            mx = fmaxf(mx, v);
        }
#pragma unroll
        for (int off = 1; off <= 8; off <<= 1) mx = fmaxf(mx, __shfl_xor(mx, off));
        float sum = 0.f;
#pragma unroll
        for (int jf = 0; jf < 13; ++jf) {
            float e = (jf * 16 + lc <= 196) ? __expf(s[jf][r] * SCALEf - mx) : 0.f;
            s[jf][r] = e;
            sum += e;
        }
#pragma unroll
        for (int off = 1; off <= 8; off <<= 1) sum += __shfl_xor(sum, off);
        float inv = 1.0f / sum;
#pragma unroll
        for (int jf = 0; jf < 13; ++jf) s[jf][r] *= inv;
    }
    __syncthreads();  // done reading Qb/Kb

    // ---- scatter P -> Pb (A-operand layout, k=col), zero-fill k 208..223
    if (lane < 32) {
        short8 z = {0, 0, 0, 0, 0, 0, 0, 0};
        *(short8*)(Pb + (w * 7 + 6) * 512 + (32 + lane) * 8) = z;
    }
#pragma unroll
    for (int jf = 0; jf < 13; ++jf) {
#pragma unroll
        for (int r = 0; r < 4; ++r) {
            int col = jf * 16 + lc;
            int row = lg * 4 + r;
            Pb[(w * 7 + (col >> 5)) * 512 + (((col >> 3) & 3) * 16 + row) * 8 + (col & 7)] =
                (u16)f2bf(s[jf][r]);
        }
    }
    // ---- stage V (224 x 64): bf16 gather, j>=197 garbage but P=0 there
    {
        const u16* vbase = qkv_b + 2 * Cn + h * HDn + (tid & 63);
        int d = tid & 63;
#pragma unroll
        for (int k = 0; k < 7; ++k) {
            int jo = (tid >> 6) + 4 * k;     // 0..27
            short8 p;
#pragma unroll
            for (int t = 0; t < 8; ++t)
                p[t] = (short)vbase[(long)(jo * 8 + t) * (3 * Cn)];
            *(short8*)(Vb + (d >> 4) * (7 * 512) + (jo >> 2) * 512 +
                       ((jo & 3) * 16 + (d & 15)) * 8) = p;
        }
    }
    __syncthreads();

    // ---- O = P @ V
    f32x4 o[4];
#pragma unroll
    for (int df = 0; df < 4; ++df) o[df] = (f32x4){0.f, 0.f, 0.f, 0.f};
#pragma unroll
    for (int ks = 0; ks < 7; ++ks) {
        short8 pa = *(const short8*)(Pb + (w * 7 + ks) * 512 + lane * 8);
#pragma unroll
        for (int df = 0; df < 4; ++df) {
            short8 vb = *(const short8*)(Vb + (df * 7 + ks) * 512 + lane * 8);
            o[df] = __builtin_amdgcn_mfma_f32_16x16x32_bf16(pa, vb, o[df], 0, 0, 0);
        }
    }

    // ---- epilogue: * mask_attn[y[b],h,d], store bf16 (pad rows ok)
    const float* mar = ma + (long)y[b] * (Hn * HDn) + h * HDn;
#pragma unroll
    for (int df = 0; df < 4; ++df) {
        int dcol = df * 16 + lc;
        float mk = mar[dcol];
#pragma unroll
        for (int r = 0; r < 4; ++r) {
            int i = i0 + w * 16 + lg * 4 + r;
            O[((long)b * RP + i) * Cn + h * HDn + dcol] = f2bf(o[df][r] * mk);
        }
    }
}

// ---------------------------------------------------------------------------
// Final: LN(x[b,0,:]) + head. One wave per b. X padded.
// ---------------------------------------------------------------------------
__global__ __launch_bounds__(64) void final_head(const float* __restrict__ x,
                                                 const float* __restrict__ nw,
                                                 const float* __restrict__ nb,
                                                 const float* __restrict__ hw,
                                                 const float* __restrict__ hb,
                                                 float* __restrict__ out) {
    int b = blockIdx.x;
    int lane = threadIdx.x;
    const float* xr = x + (long)b * RP * Cn;  // row 0
    float v[6];
    float s = 0.f, ss = 0.f;
#pragma unroll
    for (int j = 0; j < 6; ++j) {
        v[j] = xr[lane + 64 * j];
        s += v[j];
        ss += v[j] * v[j];
    }
#pragma unroll
    for (int off = 32; off >= 1; off >>= 1) {
        s += __shfl_xor(s, off);
        ss += __shfl_xor(ss, off);
    }
    float m = s * (1.0f / Cn);
    float var = ss * (1.0f / Cn) - m * m;
    float rstd = rsqrtf(var + EPSf);
    float nvals[6];
#pragma unroll
    for (int j = 0; j < 6; ++j) {
        int c = lane + 64 * j;
        nvals[j] = (v[j] - m) * rstd * nw[c] + nb[c];
    }
    for (int c10 = 0; c10 < NCn; ++c10) {
        float p = 0.f;
#pragma unroll
        for (int j = 0; j < 6; ++j) p += nvals[j] * hw[(long)c10 * Cn + lane + 64 * j];
#pragma unroll
        for (int off = 32; off >= 1; off >>= 1) p += __shfl_xor(p, off);
        if (lane == 0) out[b * NCn + c10] = p + hb[c10];
    }
}

// ---------------------------------------------------------------------------
extern "C" void kernel_launch(void* const* d_in, const int* in_sizes, int n_in,
                              void* d_out, int out_size, void* d_ws, size_t ws_size,
                              hipStream_t stream) {
    const float* x_in     = (const float*)d_in[0];
    const int*   y        = (const int*)d_in[1];
    const float* patch_w  = (const float*)d_in[2];
    const float* patch_b  = (const float*)d_in[3];
    const float* cls_tok  = (const float*)d_in[4];
    const float* pos_emb  = (const float*)d_in[5];
    const float* n1_w     = (const float*)d_in[6];
    const float* n1_b     = (const float*)d_in[7];
    const float* qkv_w    = (const float*)d_in[8];
    const float* qkv_b    = (const float*)d_in[9];
    const float* proj_w   = (const float*)d_in[10];
    const float* proj_b   = (const float*)d_in[11];
    const float* mask_attn= (const float*)d_in[12];
    const float* mask_proj= (const float*)d_in[13];
    const float* n2_w     = (const float*)d_in[14];
    const float* n2_b     = (const float*)d_in[15];
    const float* fc1_w    = (const float*)d_in[16];
    const float* fc1_b    = (const float*)d_in[17];
    const float* fc2_w    = (const float*)d_in[18];
    const float* fc2_b    = (const float*)d_in[19];
    const float* mask_fc1 = (const float*)d_in[20];
    const float* mask_fc2 = (const float*)d_in[21];
    const float* norm_w   = (const float*)d_in[22];
    const float* norm_b   = (const float*)d_in[23];
    const float* head_w   = (const float*)d_in[24];
    const float* head_b   = (const float*)d_in[25];

    // ---- workspace layout (bytes) ----
    char* base = (char*)d_ws;
    float* X   = (float*)base;                       base += (long)Bn * RP * Cn * 4;    // 12.58MB
    u16*   T   = (u16*)base;                         base += (long)Bn * RP * Cn * 2;    // 6.29MB
    u16*   QKV = (u16*)base;                         base += (long)Bn * RP * 3 * Cn * 2;// 18.87MB
    u16*   O   = (u16*)base;                         base += (long)Bn * RP * Cn * 2;    // 6.29MB
    u16*   FFb = (u16*)base;                         base += (long)Bn * RP * FFn * 2;   // 25.17MB
    u16*   COL = (u16*)base;                         base += (long)Bn * NPATCH * 768 * 2; // 9.63MB
    u16*   WQ  = (u16*)base;                         base += (long)Dn * 3 * Cn * Cn * 2;  // 5.31MB
    u16*   WP  = (u16*)base;                         base += (long)Cn * 768 * 2;          // 0.59MB
    u16*   WMp = (u16*)base;                         base += (long)NCn * Cn * Cn * 2;     // proj masked
    u16*   WMf1= (u16*)base;                         base += (long)NCn * FFn * Cn * 2;
    u16*   WMf2= (u16*)base;                         base += (long)NCn * Cn * FFn * 2;
    float* PTMP= (float*)FFb;  // alias: patch tmp (9.6MB <= 25MB), used pre-loop only

    const long sX = (long)RP * Cn;      // f32 elems per batch
    const long sT = (long)RP * Cn;      // u16 elems per batch
    const long sF = (long)RP * FFn;

    // ---- weight conversions ----
    cvtbf_kernel<<<1296, 256, 0, stream>>>(qkv_w, WQ);      // 6*1152*384 / 2048
    cvtbf_kernel<<<144, 256, 0, stream>>>(patch_w, WP);     // 384*768 / 2048

    // ---- patch embed ----
    im2col_kernel<<<18816, 256, 0, stream>>>(x_in, COL);    // 32*196*768 / 256
    gemm_bf16<3, 1><<<dim3(49, 3, 1), 256, 0, stream>>>(
        COL, 0, WP, 0, nullptr, patch_b, PTMP, 0, Cn, 768, 3);
    assemble_kernel<<<9456, 256, 0, stream>>>(PTMP, cls_tok, pos_emb, X);

    for (int l = 0; l < Dn; ++l) {
        // masked weight precompute for this layer (bf16, per class)
        maskmul_kernel<<<dim3(72, NCn), 256, 0, stream>>>(
            proj_w + (long)l * Cn * Cn, mask_proj + (long)l * NCn * Cn * Cn, WMp, Cn * Cn);
        maskmul_kernel<<<dim3(288, NCn), 256, 0, stream>>>(
            fc1_w + (long)l * FFn * Cn, mask_fc1 + (long)l * NCn * FFn * Cn, WMf1, FFn * Cn);
        maskmul_kernel<<<dim3(288, NCn), 256, 0, stream>>>(
            fc2_w + (long)l * Cn * FFn, mask_fc2 + (long)l * NCn * Cn * FFn, WMf2, Cn * FFn);

        // t = LN(x; n1)
        ln_kernel<<<Bn * Nn, 64, 0, stream>>>(X, n1_w + l * Cn, n1_b + l * Cn, T);
        // qkv = t @ qw^T + qb  (M=8192 padded, N=1152, K=384)
        gemm_bf16<0, 1><<<dim3(64, 9, 1), 256, 0, stream>>>(
            T, 0, WQ + (long)l * 3 * Cn * Cn, 0, nullptr, qkv_b + (long)l * 3 * Cn,
            QKV, 0, 3 * Cn, Cn, 9);
        // fused attention
        attn_fused<<<dim3(4, Bn * Hn), 256, 0, stream>>>(
            QKV, mask_attn + (long)l * NCn * Hn * HDn, y, O);
        // x += o @ Wm_proj[y]^T + pb   (split-K 2, atomic)
        gemm_bf16<2, 2><<<dim3(2, 6, Bn), 256, 0, stream>>>(
            O, sT, WMp, (long)Cn * Cn, y, proj_b + l * Cn, X, sX, Cn, Cn, 3);
        // t = LN(x; n2)
        ln_kernel<<<Bn * Nn, 64, 0, stream>>>(X, n2_w + l * Cn, n2_b + l * Cn, T);
        // ff = gelu(t @ Wm_fc1[y]^T + f1b)
        gemm_bf16<1, 1><<<dim3(2, 12, Bn), 256, 0, stream>>>(
            T, sT, WMf1, (long)FFn * Cn, y, fc1_b + (long)l * FFn, FFb, sF, FFn, Cn, 12);
        // x += ff @ Wm_fc2[y]^T + f2b  (split-K 2, atomic)
        gemm_bf16<2, 2><<<dim3(2, 6, Bn), 256, 0, stream>>>(
            FFb, sF, WMf2, (long)Cn * FFn, y, fc2_b + l * Cn, X, sX, Cn, FFn, 3);
    }

    final_head<<<Bn, 64, 0, stream>>>(X, norm_w, norm_b, head_w, head_b, (float*)d_out);
}

// Round 5
// 1023.143 us; speedup vs baseline: 5.5617x; 1.0645x over previous
//
#include <hip/hip_runtime.h>
#include <hip/hip_bf16.h>
#include <math.h>

// Problem constants
#define Dn 6
#define Bn 32
#define Cn 384
#define Hn 6
#define HDn 64
#define FFn 1536
#define NCn 10
#define IMGn 224
#define Nn 197
#define NPATCH 196
#define RP 256            // padded rows per batch
#define SCALEf 0.125f
#define EPSf 1e-6f

typedef unsigned short u16;
typedef __attribute__((ext_vector_type(8))) short short8;
typedef __attribute__((ext_vector_type(4))) float f32x4;

__device__ __forceinline__ u16 f2bf(float f) {
    unsigned u = __float_as_uint(f);
    return (u16)((u + 0x7FFFu + ((u >> 16) & 1u)) >> 16);
}

__device__ __forceinline__ void gload16(const void* g, void* l) {
    __builtin_amdgcn_global_load_lds((const __attribute__((address_space(1))) void*)g,
                                     (__attribute__((address_space(3))) void*)l, 16, 0, 0);
}

// ---------------------------------------------------------------------------
// cvt f32 -> bf16, 8 elems/thread, count % 2048 == 0
// ---------------------------------------------------------------------------
__global__ __launch_bounds__(256) void cvtbf_kernel(const float* __restrict__ in,
                                                    u16* __restrict__ out) {
    long off = ((long)blockIdx.x * 256 + threadIdx.x) * 8;
    float4 v0 = *(const float4*)(in + off);
    float4 v1 = *(const float4*)(in + off + 4);
    short8 p;
    p[0] = f2bf(v0.x); p[1] = f2bf(v0.y); p[2] = f2bf(v0.z); p[3] = f2bf(v0.w);
    p[4] = f2bf(v1.x); p[5] = f2bf(v1.y); p[6] = f2bf(v1.z); p[7] = f2bf(v1.w);
    *(short8*)(out + off) = p;
}

// ---------------------------------------------------------------------------
// merged masked-weight precompute for one layer:
// seg 0: proj (NK=Cn*Cn, 720 blocks), seg 1: fc1, seg 2: fc2 (NK=FFn*Cn, 2880)
// out[c*NK+i] = bf16(W[i] * mask[c*NK+i]); 8 elems/thread
// ---------------------------------------------------------------------------
__global__ __launch_bounds__(256) void maskmul3_kernel(
    const float* __restrict__ pw, const float* __restrict__ mp,
    const float* __restrict__ f1w, const float* __restrict__ mf1,
    const float* __restrict__ f2w, const float* __restrict__ mf2,
    u16* __restrict__ WMp, u16* __restrict__ WMf1, u16* __restrict__ WMf2) {
    int seg = blockIdx.y;
    const float* W; const float* M; u16* O; int NK; int nblk;
    if (seg == 0)      { W = pw;  M = mp;  O = WMp;  NK = Cn * Cn;  nblk = 720; }
    else if (seg == 1) { W = f1w; M = mf1; O = WMf1; NK = FFn * Cn; nblk = 2880; }
    else               { W = f2w; M = mf2; O = WMf2; NK = Cn * FFn; nblk = 2880; }
    if (blockIdx.x >= nblk) return;
    long e = ((long)blockIdx.x * 256 + threadIdx.x) * 8;
    int c = (int)(e / NK);
    int wi = (int)(e - (long)c * NK);
    float4 w0 = *(const float4*)(W + wi);
    float4 w1 = *(const float4*)(W + wi + 4);
    float4 m0 = *(const float4*)(M + e);
    float4 m1 = *(const float4*)(M + e + 4);
    short8 p;
    p[0] = f2bf(w0.x * m0.x); p[1] = f2bf(w0.y * m0.y);
    p[2] = f2bf(w0.z * m0.z); p[3] = f2bf(w0.w * m0.w);
    p[4] = f2bf(w1.x * m1.x); p[5] = f2bf(w1.y * m1.y);
    p[6] = f2bf(w1.z * m1.z); p[7] = f2bf(w1.w * m1.w);
    *(short8*)(O + e) = p;
}

// ---------------------------------------------------------------------------
// im2col -> bf16: x (B,3,224,224) -> col (B*196, 768)
// ---------------------------------------------------------------------------
__global__ __launch_bounds__(256) void im2col_kernel(const float* __restrict__ x,
                                                     u16* __restrict__ col) {
    long idx = (long)blockIdx.x * 256 + threadIdx.x;
    int k = (int)(idx % 768);
    long row = idx / 768;
    int b = (int)(row / NPATCH), p = (int)(row % NPATCH);
    int i = k / 256, r = k % 256, ph = r / 16, pw = r % 16;
    int py = p / 14, px = p % 14;
    col[idx] = f2bf(x[(((long)b * 3 + i) * IMGn + py * 16 + ph) * IMGn + px * 16 + pw]);
}

// ---------------------------------------------------------------------------
// assemble x (f32, padded)
// ---------------------------------------------------------------------------
__global__ __launch_bounds__(256) void assemble_kernel(const float* __restrict__ tmp,
                                                       const float* __restrict__ cls_token,
                                                       const float* __restrict__ pos,
                                                       float* __restrict__ x) {
    long idx = (long)blockIdx.x * 256 + threadIdx.x;
    const long total = (long)Bn * Nn * Cn;
    if (idx >= total) return;
    int c = (int)(idx % Cn);
    long rem = idx / Cn;
    int n = (int)(rem % Nn);
    int b = (int)(rem / Nn);
    float v;
    if (n == 0) v = cls_token[c];
    else v = tmp[((long)b * NPATCH + (n - 1)) * Cn + c];
    x[((long)b * RP + n) * Cn + c] = v + pos[n * Cn + c];
}

// ---------------------------------------------------------------------------
// LayerNorm: X f32 padded -> T bf16 padded. One wave per (b,n) row.
// ---------------------------------------------------------------------------
__global__ __launch_bounds__(64) void ln_kernel(const float* __restrict__ x,
                                                const float* __restrict__ w,
                                                const float* __restrict__ b,
                                                u16* __restrict__ out) {
    long blk = blockIdx.x;
    int bb = (int)(blk / Nn), n = (int)(blk % Nn);
    long row = (long)bb * RP + n;
    int lane = threadIdx.x;
    const float* xr = x + row * Cn;
    float v[6];
    float s = 0.f, ss = 0.f;
#pragma unroll
    for (int j = 0; j < 6; ++j) {
        v[j] = xr[lane + 64 * j];
        s += v[j];
        ss += v[j] * v[j];
    }
#pragma unroll
    for (int off = 32; off >= 1; off >>= 1) {
        s += __shfl_xor(s, off);
        ss += __shfl_xor(ss, off);
    }
    float m = s * (1.0f / Cn);
    float var = ss * (1.0f / Cn) - m * m;
    float rstd = rsqrtf(var + EPSf);
#pragma unroll
    for (int j = 0; j < 6; ++j) {
        int c = lane + 64 * j;
        out[row * Cn + c] = f2bf((v[j] - m) * rstd * w[c] + b[c]);
    }
}

// ---------------------------------------------------------------------------
// bf16 MFMA GEMM, tile MTx128, K-step 32, double-buffered global_load_lds.
// Out[m,o] (+)= sum_k A[m,k]*W[o,k] + bias[o]
// EPI: 0 = store bf16, 1 = gelu+store bf16, 2 = f32 +=, 3 = store f32.
// MT in {64,128}. M%MT==0 (padded), N%128==0, K%32==0.
// grid: (M/MT, NTILES, Z)
// ---------------------------------------------------------------------------
template <int EPI, int MT>
__global__ __launch_bounds__(256) void gemm_bf16(
    const u16* __restrict__ A, long strideA,
    const u16* __restrict__ Wb, long wClassStride,
    const int* __restrict__ y,
    const float* __restrict__ bias,
    void* __restrict__ OutV, long strideO,
    int Nout, int Ktot) {
    const int bz = blockIdx.z;
    A += (long)bz * strideA;
    const u16* Wp = Wb + (y ? (long)y[bz] * wClassStride : 0);

    constexpr int ASUB = MT / 16;        // A subtiles per k-step
    constexpr int AI = MT / 32;          // A frags per wave
    __shared__ alignas(16) u16 Ab[2][ASUB * 512];
    __shared__ alignas(16) u16 Bb[2][4096];

    const int tid = threadIdx.x;
    const int lane = tid & 63;
    const int w = tid >> 6;
    const int wr = w >> 1, wc = w & 1;
    const int m0 = blockIdx.x * MT;
    const int n0 = blockIdx.y * 128;
    const int r15 = lane & 15, oct = lane >> 4;

    auto STAGE = [&](int k0, int bf) {
        {
            int s0 = 2 * w;
            const u16* b0 = Wp + (long)(n0 + 16 * s0 + r15) * Ktot + k0 + oct * 8;
            gload16(b0, &Bb[bf][s0 * 512]);
            gload16(b0 + 16 * (long)Ktot, &Bb[bf][(s0 + 1) * 512]);
        }
        if (MT == 128) {
            int s0 = 2 * w;
            const u16* a0 = A + (long)(m0 + 16 * s0 + r15) * Ktot + k0 + oct * 8;
            gload16(a0, &Ab[bf][s0 * 512]);
            gload16(a0 + 16 * (long)Ktot, &Ab[bf][(s0 + 1) * 512]);
        } else {
            const u16* a0 = A + (long)(m0 + 16 * w + r15) * Ktot + k0 + oct * 8;
            gload16(a0, &Ab[bf][w * 512]);
        }
    };

    f32x4 acc[AI][4];
#pragma unroll
    for (int i = 0; i < AI; ++i)
#pragma unroll
        for (int j = 0; j < 4; ++j) acc[i][j] = (f32x4){0.f, 0.f, 0.f, 0.f};

    const int nsteps = Ktot / 32;
    STAGE(0, 0);
    __syncthreads();
    int cur = 0;
    for (int t = 0; t < nsteps; ++t) {
        if (t + 1 < nsteps) STAGE((t + 1) * 32, cur ^ 1);
        short8 af[AI], bfr[4];
#pragma unroll
        for (int i = 0; i < AI; ++i)
            af[i] = *(const short8*)(&Ab[cur][(wr * AI + i) * 512 + lane * 8]);
#pragma unroll
        for (int j = 0; j < 4; ++j)
            bfr[j] = *(const short8*)(&Bb[cur][(wc * 4 + j) * 512 + lane * 8]);
#pragma unroll
        for (int i = 0; i < AI; ++i)
#pragma unroll
            for (int j = 0; j < 4; ++j)
                acc[i][j] = __builtin_amdgcn_mfma_f32_16x16x32_bf16(af[i], bfr[j], acc[i][j], 0, 0, 0);
        __syncthreads();
        cur ^= 1;
    }

    // epilogue: D frag mapping col=lane&15, row=(lane>>4)*4+r
    const int lr = lane >> 4;
    const int lc = lane & 15;
#pragma unroll
    for (int i = 0; i < AI; ++i) {
#pragma unroll
        for (int j = 0; j < 4; ++j) {
            int colg = n0 + (wc * 4 + j) * 16 + lc;
            float bv = bias ? bias[colg] : 0.f;
#pragma unroll
            for (int r = 0; r < 4; ++r) {
                int m = m0 + (wr * AI + i) * 16 + lr * 4 + r;
                float v = acc[i][j][r] + bv;
                long oi = (long)m * Nout + colg;
                if (EPI == 0) {
                    ((u16*)OutV + (long)bz * strideO)[oi] = f2bf(v);
                } else if (EPI == 1) {
                    v = 0.5f * v * (1.0f + erff(v * 0.70710678118654752440f));
                    ((u16*)OutV + (long)bz * strideO)[oi] = f2bf(v);
                } else if (EPI == 2) {
                    float* Out = (float*)OutV + (long)bz * strideO;
                    Out[oi] += v;
                } else {
                    ((float*)OutV + (long)bz * strideO)[oi] = v;
                }
            }
        }
    }
}

// ---------------------------------------------------------------------------
// Fused attention on bf16 QKV (padded RP rows/batch).
// One block per (i-tile of 64 rows, b*H+h).
// ---------------------------------------------------------------------------
__global__ __launch_bounds__(256) void attn_fused(const u16* __restrict__ qkv,
                                                  const float* __restrict__ ma,
                                                  const int* __restrict__ y,
                                                  u16* __restrict__ O) {
    const int it = blockIdx.x;       // 0..3
    const int bh = blockIdx.y;       // b*H + h
    const int h = bh % Hn, b = bh / Hn;
    const int i0 = it * 64;
    const int tid = threadIdx.x, lane = tid & 63, w = tid >> 6;
    const int lg = lane >> 4, lc = lane & 15;

    __shared__ alignas(16) u16 SH[31744];
    u16* Qb = SH;
    u16* Kb = SH + 4096;
    u16* Vb = SH;
    u16* Pb = SH + 17408;

    const u16* qkv_b = qkv + (long)b * RP * (3 * Cn);
    const int r15 = lane & 15;
    const int oct = lane >> 4;

    // ---- stage Q (64 x 64): 8 subtiles, 2 per wave
#pragma unroll
    for (int si = 0; si < 2; ++si) {
        int s = w * 2 + si;
        int r = (s >> 1) * 16 + r15;
        int g = (s & 1) * 4 + oct;
        const u16* src = qkv_b + (long)(i0 + r) * (3 * Cn) + h * HDn + g * 8;
        gload16(src, Qb + s * 512);
    }
    // ---- stage K (208 x 64): 26 subtiles
    for (int s = w; s < 26; s += 4) {
        int c = (s >> 1) * 16 + r15;
        int g = (s & 1) * 4 + oct;
        const u16* src = qkv_b + (long)c * (3 * Cn) + Cn + h * HDn + g * 8;
        gload16(src, Kb + s * 512);
    }
    __syncthreads();

    // ---- S = Q @ K^T
    f32x4 s[13];
#pragma unroll
    for (int jf = 0; jf < 13; ++jf) s[jf] = (f32x4){0.f, 0.f, 0.f, 0.f};
    {
        short8 a0 = *(const short8*)(Qb + (w * 2 + 0) * 512 + lane * 8);
        short8 a1 = *(const short8*)(Qb + (w * 2 + 1) * 512 + lane * 8);
#pragma unroll
        for (int jf = 0; jf < 13; ++jf) {
            short8 b0 = *(const short8*)(Kb + (jf * 2 + 0) * 512 + lane * 8);
            short8 b1 = *(const short8*)(Kb + (jf * 2 + 1) * 512 + lane * 8);
            s[jf] = __builtin_amdgcn_mfma_f32_16x16x32_bf16(a0, b0, s[jf], 0, 0, 0);
            s[jf] = __builtin_amdgcn_mfma_f32_16x16x32_bf16(a1, b1, s[jf], 0, 0, 0);
        }
    }

    // ---- in-register softmax
#pragma unroll
    for (int r = 0; r < 4; ++r) {
        float mx = -1e30f;
#pragma unroll
        for (int jf = 0; jf < 13; ++jf) {
            float v = s[jf][r] * SCALEf;
            if (jf * 16 + lc > 196) v = -1e30f;
            mx = fmaxf(mx, v);
        }
#pragma unroll
        for (int off = 1; off <= 8; off <<= 1) mx = fmaxf(mx, __shfl_xor(mx, off));
        float sum = 0.f;
#pragma unroll
        for (int jf = 0; jf < 13; ++jf) {
            float e = (jf * 16 + lc <= 196) ? __expf(s[jf][r] * SCALEf - mx) : 0.f;
            s[jf][r] = e;
            sum += e;
        }
#pragma unroll
        for (int off = 1; off <= 8; off <<= 1) sum += __shfl_xor(sum, off);
        float inv = 1.0f / sum;
#pragma unroll
        for (int jf = 0; jf < 13; ++jf) s[jf][r] *= inv;
    }
    __syncthreads();

    // ---- scatter P -> Pb (A-operand layout), zero-fill k 208..223
    if (lane < 32) {
        short8 z = {0, 0, 0, 0, 0, 0, 0, 0};
        *(short8*)(Pb + (w * 7 + 6) * 512 + (32 + lane) * 8) = z;
    }
#pragma unroll
    for (int jf = 0; jf < 13; ++jf) {
#pragma unroll
        for (int r = 0; r < 4; ++r) {
            int col = jf * 16 + lc;
            int row = lg * 4 + r;
            Pb[(w * 7 + (col >> 5)) * 512 + (((col >> 3) & 3) * 16 + row) * 8 + (col & 7)] =
                (u16)f2bf(s[jf][r]);
        }
    }
    // ---- stage V (224 x 64)
    {
        const u16* vbase = qkv_b + 2 * Cn + h * HDn + (tid & 63);
        int d = tid & 63;
#pragma unroll
        for (int k = 0; k < 7; ++k) {
            int jo = (tid >> 6) + 4 * k;
            short8 p;
#pragma unroll
            for (int t = 0; t < 8; ++t)
                p[t] = (short)vbase[(long)(jo * 8 + t) * (3 * Cn)];
            *(short8*)(Vb + (d >> 4) * (7 * 512) + (jo >> 2) * 512 +
                       ((jo & 3) * 16 + (d & 15)) * 8) = p;
        }
    }
    __syncthreads();

    // ---- O = P @ V
    f32x4 o[4];
#pragma unroll
    for (int df = 0; df < 4; ++df) o[df] = (f32x4){0.f, 0.f, 0.f, 0.f};
#pragma unroll
    for (int ks = 0; ks < 7; ++ks) {
        short8 pa = *(const short8*)(Pb + (w * 7 + ks) * 512 + lane * 8);
#pragma unroll
        for (int df = 0; df < 4; ++df) {
            short8 vb = *(const short8*)(Vb + (df * 7 + ks) * 512 + lane * 8);
            o[df] = __builtin_amdgcn_mfma_f32_16x16x32_bf16(pa, vb, o[df], 0, 0, 0);
        }
    }

    // ---- epilogue: * mask_attn[y[b],h,d], store bf16
    const float* mar = ma + (long)y[b] * (Hn * HDn) + h * HDn;
#pragma unroll
    for (int df = 0; df < 4; ++df) {
        int dcol = df * 16 + lc;
        float mk = mar[dcol];
#pragma unroll
        for (int r = 0; r < 4; ++r) {
            int i = i0 + w * 16 + lg * 4 + r;
            O[((long)b * RP + i) * Cn + h * HDn + dcol] = f2bf(o[df][r] * mk);
        }
    }
}

// ---------------------------------------------------------------------------
// Final: LN(x[b,0,:]) + head. One wave per b.
// ---------------------------------------------------------------------------
__global__ __launch_bounds__(64) void final_head(const float* __restrict__ x,
                                                 const float* __restrict__ nw,
                                                 const float* __restrict__ nb,
                                                 const float* __restrict__ hw,
                                                 const float* __restrict__ hb,
                                                 float* __restrict__ out) {
    int b = blockIdx.x;
    int lane = threadIdx.x;
    const float* xr = x + (long)b * RP * Cn;
    float v[6];
    float s = 0.f, ss = 0.f;
#pragma unroll
    for (int j = 0; j < 6; ++j) {
        v[j] = xr[lane + 64 * j];
        s += v[j];
        ss += v[j] * v[j];
    }
#pragma unroll
    for (int off = 32; off >= 1; off >>= 1) {
        s += __shfl_xor(s, off);
        ss += __shfl_xor(ss, off);
    }
    float m = s * (1.0f / Cn);
    float var = ss * (1.0f / Cn) - m * m;
    float rstd = rsqrtf(var + EPSf);
    float nvals[6];
#pragma unroll
    for (int j = 0; j < 6; ++j) {
        int c = lane + 64 * j;
        nvals[j] = (v[j] - m) * rstd * nw[c] + nb[c];
    }
    for (int c10 = 0; c10 < NCn; ++c10) {
        float p = 0.f;
#pragma unroll
        for (int j = 0; j < 6; ++j) p += nvals[j] * hw[(long)c10 * Cn + lane + 64 * j];
#pragma unroll
        for (int off = 32; off >= 1; off >>= 1) p += __shfl_xor(p, off);
        if (lane == 0) out[b * NCn + c10] = p + hb[c10];
    }
}

// ---------------------------------------------------------------------------
extern "C" void kernel_launch(void* const* d_in, const int* in_sizes, int n_in,
                              void* d_out, int out_size, void* d_ws, size_t ws_size,
                              hipStream_t stream) {
    const float* x_in     = (const float*)d_in[0];
    const int*   y        = (const int*)d_in[1];
    const float* patch_w  = (const float*)d_in[2];
    const float* patch_b  = (const float*)d_in[3];
    const float* cls_tok  = (const float*)d_in[4];
    const float* pos_emb  = (const float*)d_in[5];
    const float* n1_w     = (const float*)d_in[6];
    const float* n1_b     = (const float*)d_in[7];
    const float* qkv_w    = (const float*)d_in[8];
    const float* qkv_b    = (const float*)d_in[9];
    const float* proj_w   = (const float*)d_in[10];
    const float* proj_b   = (const float*)d_in[11];
    const float* mask_attn= (const float*)d_in[12];
    const float* mask_proj= (const float*)d_in[13];
    const float* n2_w     = (const float*)d_in[14];
    const float* n2_b     = (const float*)d_in[15];
    const float* fc1_w    = (const float*)d_in[16];
    const float* fc1_b    = (const float*)d_in[17];
    const float* fc2_w    = (const float*)d_in[18];
    const float* fc2_b    = (const float*)d_in[19];
    const float* mask_fc1 = (const float*)d_in[20];
    const float* mask_fc2 = (const float*)d_in[21];
    const float* norm_w   = (const float*)d_in[22];
    const float* norm_b   = (const float*)d_in[23];
    const float* head_w   = (const float*)d_in[24];
    const float* head_b   = (const float*)d_in[25];

    // ---- workspace layout ----
    char* base = (char*)d_ws;
    float* X   = (float*)base;                       base += (long)Bn * RP * Cn * 4;
    u16*   T   = (u16*)base;                         base += (long)Bn * RP * Cn * 2;
    u16*   QKV = (u16*)base;                         base += (long)Bn * RP * 3 * Cn * 2;
    u16*   O   = (u16*)base;                         base += (long)Bn * RP * Cn * 2;
    u16*   FFb = (u16*)base;                         base += (long)Bn * RP * FFn * 2;
    u16*   COL = (u16*)base;                         base += (long)Bn * NPATCH * 768 * 2;
    u16*   WQ  = (u16*)base;                         base += (long)Dn * 3 * Cn * Cn * 2;
    u16*   WP  = (u16*)base;                         base += (long)Cn * 768 * 2;
    u16*   WMp = (u16*)base;                         base += (long)NCn * Cn * Cn * 2;
    u16*   WMf1= (u16*)base;                         base += (long)NCn * FFn * Cn * 2;
    u16*   WMf2= (u16*)base;                         base += (long)NCn * Cn * FFn * 2;
    float* PTMP= (float*)FFb;  // alias: patch tmp, used pre-loop only

    const long sX = (long)RP * Cn;
    const long sT = (long)RP * Cn;
    const long sF = (long)RP * FFn;

    // ---- weight conversions ----
    cvtbf_kernel<<<1296, 256, 0, stream>>>(qkv_w, WQ);
    cvtbf_kernel<<<144, 256, 0, stream>>>(patch_w, WP);

    // ---- patch embed ----
    im2col_kernel<<<18816, 256, 0, stream>>>(x_in, COL);
    gemm_bf16<3, 64><<<dim3(98, 3, 1), 256, 0, stream>>>(
        COL, 0, WP, 0, nullptr, patch_b, PTMP, 0, Cn, 768);
    assemble_kernel<<<9456, 256, 0, stream>>>(PTMP, cls_tok, pos_emb, X);

    for (int l = 0; l < Dn; ++l) {
        // masked weight precompute (bf16, per class) — one launch
        maskmul3_kernel<<<dim3(2880, 3), 256, 0, stream>>>(
            proj_w + (long)l * Cn * Cn, mask_proj + (long)l * NCn * Cn * Cn,
            fc1_w + (long)l * FFn * Cn, mask_fc1 + (long)l * NCn * FFn * Cn,
            fc2_w + (long)l * Cn * FFn, mask_fc2 + (long)l * NCn * Cn * FFn,
            WMp, WMf1, WMf2);

        // t = LN(x; n1)
        ln_kernel<<<Bn * Nn, 64, 0, stream>>>(X, n1_w + l * Cn, n1_b + l * Cn, T);
        // qkv = t @ qw^T + qb  (M=8192 padded, N=1152, K=384)
        gemm_bf16<0, 128><<<dim3(64, 9, 1), 256, 0, stream>>>(
            T, 0, WQ + (long)l * 3 * Cn * Cn, 0, nullptr, qkv_b + (long)l * 3 * Cn,
            QKV, 0, 3 * Cn, Cn);
        // fused attention
        attn_fused<<<dim3(4, Bn * Hn), 256, 0, stream>>>(
            QKV, mask_attn + (long)l * NCn * Hn * HDn, y, O);
        // x += o @ Wm_proj[y]^T + pb
        gemm_bf16<2, 64><<<dim3(4, 3, Bn), 256, 0, stream>>>(
            O, sT, WMp, (long)Cn * Cn, y, proj_b + l * Cn, X, sX, Cn, Cn);
        // t = LN(x; n2)
        ln_kernel<<<Bn * Nn, 64, 0, stream>>>(X, n2_w + l * Cn, n2_b + l * Cn, T);
        // ff = gelu(t @ Wm_fc1[y]^T + f1b)
        gemm_bf16<1, 128><<<dim3(2, 12, Bn), 256, 0, stream>>>(
            T, sT, WMf1, (long)FFn * Cn, y, fc1_b + (long)l * FFn, FFb, sF, FFn, Cn);
        // x += ff @ Wm_fc2[y]^T + f2b
        gemm_bf16<2, 64><<<dim3(4, 3, Bn), 256, 0, stream>>>(
            FFb, sF, WMf2, (long)Cn * FFn, y, fc2_b + l * Cn, X, sX, Cn, FFn);
    }

    final_head<<<Bn, 64, 0, stream>>>(X, norm_w, norm_b, head_w, head_b, (float*)d_out);
}